// Round 7
// baseline (957.895 us; speedup 1.0000x reference)
//
#include <hip/hip_runtime.h>

#define BB 8
#define NN 4096
#define DD 256
#define HH 4
#define DHH 64
#define KPP 256
#define KNN 128
#define SCH 64   // stats chunks per batch (64 rows each)

typedef float f32x4 __attribute__((ext_vector_type(4)));
typedef short bf16x8 __attribute__((ext_vector_type(8)));
typedef short bf16x4 __attribute__((ext_vector_type(4)));

#define FLAG_TRANSB 1
#define FLAG_RELU   2

__device__ __forceinline__ float bf2f(unsigned short u){
  union { unsigned int i; float f; } v; v.i = ((unsigned int)u) << 16; return v.f;
}
__device__ __forceinline__ unsigned short f2bf(float f){
  union { float f; unsigned int i; } v; v.f = f;
  return (unsigned short)((v.i + 0x7FFFu + ((v.i >> 16) & 1u)) >> 16);
}
__device__ __forceinline__ void gload16(const void* g, void* l){
  __builtin_amdgcn_global_load_lds((const __attribute__((address_space(1))) void*)g,
                                   (__attribute__((address_space(3))) void*)l, 16, 0, 0);
}

// ---------------- device-scope global barrier (all gridDim.x blocks co-resident) ----------------
__device__ __forceinline__ void gbar(unsigned int* c, unsigned int n){
  __syncthreads();
  if (threadIdx.x == 0){
    __threadfence();   // release: flush this block's writes to device scope
    __hip_atomic_fetch_add(c, 1u, __ATOMIC_RELEASE, __HIP_MEMORY_SCOPE_AGENT);
    while (__hip_atomic_load(c, __ATOMIC_ACQUIRE, __HIP_MEMORY_SCOPE_AGENT) < n)
      __builtin_amdgcn_s_sleep(8);
  }
  __syncthreads();
}

// ---------------- merged fold_all + stats_part (independent work, one launch) ----------------
struct FoldArgs { const float* W[9]; const float* g[9]; unsigned short* BT[9]; float sc[9]; };
struct BiasArgs { const float* W[7]; const float* b[7]; const float* addb[7]; float* out[7]; float sc[7]; };

__global__ __launch_bounds__(256) void fold_stats(FoldArgs fa, BiasArgs ba,
                                                  const float* __restrict__ x,
                                                  const int* __restrict__ mask,
                                                  float* __restrict__ part,
                                                  float* __restrict__ pcnt){
  __shared__ __align__(16) char smem[16640];
  int t = threadIdx.x;
  int by = blockIdx.y;
  if (by < 9){
    if (blockIdx.x >= 16) return;
    float (*T)[65] = (float(*)[65])smem;
    int m = by, tile = blockIdx.x;
    const float* W = fa.W[m]; const float* g = fa.g[m]; unsigned short* BT = fa.BT[m];
    float sc = fa.sc[m];
    int tn = (tile & 3)*64, tk = (tile >> 2)*64;
    #pragma unroll 4
    for (int p = 0; p < 16; p++){
      int kl = p*4 + (t >> 6), nl = t & 63;
      float v = W[(long)(tk+kl)*256 + tn + nl];
      if (g) v *= g[tk+kl];
      T[kl][nl] = v * sc;
    }
    __syncthreads();
    #pragma unroll 4
    for (int p = 0; p < 16; p++){
      int nl = p*4 + (t >> 6), kl = t & 63;
      BT[(long)(tn+nl)*256 + tk + kl] = f2bf(T[kl][nl]);
    }
  } else if (by == 9){
    if (blockIdx.x >= 7) return;
    int m = blockIdx.x, n = t;
    const float* W = ba.W[m]; const float* b = ba.b[m];
    float s = (ba.addb[m] != nullptr) ? ba.addb[m][n] : 0.f;
    for (int k = 0; k < 256; k++) s += b[k]*W[(long)k*256+n];
    ba.out[m][n] = s * ba.sc[m];
  } else {
    int b = by - 10, c = blockIdx.x;
    int w = t >> 6, lane = t & 63;
    const int R = NN / SCH;           // 64 rows per chunk
    int n0 = c * R;
    const float* xb = x + ((long)b*NN + n0)*DD;
    const int* mb = mask + (long)b*NN + n0;
    float4 sp = {0.f,0.f,0.f,0.f}, sn = {0.f,0.f,0.f,0.f};
    int cp = 0, cn = 0;
    #pragma unroll 4
    for (int r = w; r < R; r += 4){
      int mv = mb[r];
      float4 v = ((const float4*)(xb + (long)r*DD))[lane];
      if (mv == 1){ sp.x += v.x; sp.y += v.y; sp.z += v.z; sp.w += v.w; cp++; }
      else if (mv == -1){ sn.x += v.x; sn.y += v.y; sn.z += v.z; sn.w += v.w; cn++; }
    }
    float (*red)[4][256] = (float(*)[4][256])smem;
    int* cnt = (int*)(smem + 8192);
    ((float4*)&red[0][w][0])[lane] = sp;
    ((float4*)&red[1][w][0])[lane] = sn;
    if (lane == 0){ cnt[w] = cp; cnt[4+w] = cn; }
    __syncthreads();
    float s0 = red[0][0][t]+red[0][1][t]+red[0][2][t]+red[0][3][t];
    float s1 = red[1][0][t]+red[1][1][t]+red[1][2][t]+red[1][3][t];
    part[(((long)(b*SCH+c)*2+0)*DD)+t] = s0;
    part[(((long)(b*SCH+c)*2+1)*DD)+t] = s1;
    if (t == 0){
      pcnt[(b*SCH+c)*2+0] = (float)(cnt[0]+cnt[1]+cnt[2]+cnt[3]);
      pcnt[(b*SCH+c)*2+1] = (float)(cnt[4]+cnt[5]+cnt[6]+cnt[7]);
    }
  }
}

// ---------------- merged stats reduce + matvec + cscal (one launch) ----------------
// blocks (c,b): every block re-reduces part -> qp/qn in LDS (L2-resident, ~2us total);
// c<8 computes matvec rows [c*32, c*32+32); c==8 computes cscal.
__global__ void stats_sim(const float* __restrict__ part, const float* __restrict__ pcnt,
                          const float* __restrict__ Wp, const float* __restrict__ Wn,
                          const float* __restrict__ bp, const float* __restrict__ bn,
                          float* __restrict__ vvec, float* __restrict__ cscal){
  int c = blockIdx.x, b = blockIdx.y, t = threadIdx.x;
  __shared__ float qp[256], qn[256], red[256];
  {
    float sp=0.f, sn=0.f, cp=0.f, cn=0.f;
    for (int ch = 0; ch < SCH; ch++){
      sp += part[(((long)(b*SCH+ch)*2+0)*DD)+t];
      sn += part[(((long)(b*SCH+ch)*2+1)*DD)+t];
      cp += pcnt[(b*SCH+ch)*2+0];
      cn += pcnt[(b*SCH+ch)*2+1];
    }
    qp[t] = sp / (cp + 1e-6f);
    qn[t] = sn / (cn + 1e-6f);
  }
  __syncthreads();
  if (c < 8){
    int row = c*32 + (t >> 3);
    int seg = (t & 7)*32;
    const float* wp = Wp + (long)row*DD + seg;
    const float* wn = Wn + (long)row*DD + seg;
    float ap = 0.f, an = 0.f;
    #pragma unroll 8
    for (int j = 0; j < 32; j++){ ap += wp[j]*qp[seg+j]; an += wn[j]*qn[seg+j]; }
    #pragma unroll
    for (int off = 1; off < 8; off <<= 1){ ap += __shfl_xor(ap, off); an += __shfl_xor(an, off); }
    if ((t & 7) == 0){
      vvec[(long)(b*2+0)*DD + row] = ap;
      vvec[(long)(b*2+1)*DD + row] = an;
    }
  } else {
    red[t] = bp[t]*qp[t];
    __syncthreads();
    for (int s = 128; s > 0; s >>= 1){ if (t < s) red[t] += red[t+s]; __syncthreads(); }
    if (t == 0) cscal[b*2+0] = red[0];
    __syncthreads();
    red[t] = bn[t]*qn[t];
    __syncthreads();
    for (int s = 128; s > 0; s >>= 1){ if (t < s) red[t] += red[t+s]; __syncthreads(); }
    if (t == 0) cscal[b*2+1] = red[0];
  }
}

// ---------------- fused sims + LN-core of x ----------------
__global__ void sim_norm_kernel(const float* __restrict__ x, const float* __restrict__ vvec,
                                const float* __restrict__ cscal,
                                float* __restrict__ simP, float* __restrict__ simN,
                                unsigned short* __restrict__ xhat){
  int b = blockIdx.y;
  int w = threadIdx.x >> 6, lane = threadIdx.x & 63;
  int n = blockIdx.x*4 + w;
  long row = (long)b*NN + n;
  const float4* xr = (const float4*)(x + row*DD);
  float4 xv = xr[lane];
  float4 a = ((const float4*)(vvec + (long)(b*2+0)*DD))[lane];
  float4 c = ((const float4*)(vvec + (long)(b*2+1)*DD))[lane];
  float sp = xv.x*a.x + xv.y*a.y + xv.z*a.z + xv.w*a.w;
  float sn = xv.x*c.x + xv.y*c.y + xv.z*c.z + xv.w*c.w;
  float s  = xv.x+xv.y+xv.z+xv.w;
  float q  = xv.x*xv.x+xv.y*xv.y+xv.z*xv.z+xv.w*xv.w;
  for (int off = 32; off; off >>= 1){
    sp += __shfl_xor(sp, off); sn += __shfl_xor(sn, off);
    s  += __shfl_xor(s, off);  q  += __shfl_xor(q, off);
  }
  float m = s*(1.f/256.f);
  float var = q*(1.f/256.f) - m*m;
  float rinv = rsqrtf(var + 1e-5f);
  ushort4 o;
  o.x = f2bf((xv.x-m)*rinv); o.y = f2bf((xv.y-m)*rinv);
  o.z = f2bf((xv.z-m)*rinv); o.w = f2bf((xv.w-m)*rinv);
  ((ushort4*)(xhat + row*DD))[lane] = o;
  if (lane == 0){
    float zp = sp + cscal[b*2+0], zn = sn + cscal[b*2+1];
    simP[row] = 1.f/(1.f+expf(-zp));
    simN[row] = 1.f/(1.f+expf(-zn));
  }
}

// ---------------- top-k (3-pass radix, parallel scans) + fused node gather ----------------
__global__ __launch_bounds__(256) void topk_radix(const float* __restrict__ simP,
                                                  const float* __restrict__ simN,
                                                  const float* __restrict__ x,
                                                  int* __restrict__ idxb, float* __restrict__ wb,
                                                  float* __restrict__ node){
  __shared__ unsigned int vals[4096];
  __shared__ unsigned int hist[4096];
  __shared__ unsigned short eql[4096];
  __shared__ unsigned int tsum[256];
  __shared__ unsigned int sB, sRem, sCG, sCnt, sEq;
  int id = blockIdx.x; int sgn = id & 1, b = id >> 1;
  int K = (sgn == 0) ? KPP : KNN;
  const float* s = (sgn == 0 ? simP : simN) + (long)b*NN;
  int t = threadIdx.x;
  if (t == 0){ sCG = 0; sCnt = 0; sEq = 0; }
  for (int i = t; i < 4096; i += 256){ vals[i] = __float_as_uint(s[i]); hist[i] = 0; }
  __syncthreads();

  auto find_thresh = [&](int NB, unsigned need){
    int per = NB >> 8;
    int base = t*per;
    unsigned local = 0;
    for (int j = 0; j < per; j++) local += hist[base+j];
    tsum[t] = local;
    __syncthreads();
    #pragma unroll
    for (int st = 1; st < 256; st <<= 1){
      unsigned v = (t + st < 256) ? tsum[t+st] : 0u;
      __syncthreads();
      tsum[t] += v;
      __syncthreads();
    }
    unsigned after = (t < 255) ? tsum[t+1] : 0u;
    if (after < need && after + local >= need){
      unsigned c = after;
      for (int j = per-1; j >= 0; j--){
        unsigned h = hist[base+j];
        c += h;
        if (c >= need){
          sB = (unsigned)(base+j);
          sRem = need - (c - h);
          atomicAdd(&sCG, c - h);
          break;
        }
      }
    }
    __syncthreads();
  };

  for (int i = t; i < 4096; i += 256) atomicAdd(&hist[vals[i] >> 20], 1u);
  __syncthreads();
  find_thresh(4096, (unsigned)K);
  unsigned B1 = sB, rem1 = sRem;
  __syncthreads();
  for (int i = t; i < 4096; i += 256) hist[i] = 0;
  __syncthreads();
  for (int i = t; i < 4096; i += 256){
    unsigned v = vals[i];
    if ((v >> 20) == B1) atomicAdd(&hist[(v >> 8) & 0xFFFu], 1u);
  }
  __syncthreads();
  find_thresh(4096, rem1);
  unsigned B2 = sB, rem2 = sRem;
  unsigned pre = (B1 << 12) | B2;
  __syncthreads();
  hist[t] = 0;
  __syncthreads();
  for (int i = t; i < 4096; i += 256){
    unsigned v = vals[i];
    if ((v >> 8) == pre) atomicAdd(&hist[v & 0xFFu], 1u);
  }
  __syncthreads();
  find_thresh(256, rem2);
  unsigned T = (pre << 8) | sB;
  unsigned cg2 = sCG;
  __syncthreads();
  hist[t] = 0;
  __syncthreads();

  int* oi = idxb + (long)id*256;
  float* ow = wb + (long)id*256;
  for (int i = t; i < 4096; i += 256){
    unsigned v = vals[i];
    if (v > T){
      unsigned p = atomicAdd(&sCnt, 1u);
      oi[p] = i; ow[p] = __uint_as_float(v);
      hist[p] = (unsigned)i; hist[256+p] = v;
    }
    else if (v == T){ unsigned e = atomicAdd(&sEq, 1u); eql[e] = (unsigned short)i; }
  }
  __syncthreads();
  int ne = K - (int)cg2;
  int eqn = (int)sEq;
  for (int e = t; e < eqn; e += 256){
    int myi = eql[e]; int r = 0;
    for (int e2 = 0; e2 < eqn; e2++) r += (eql[e2] < myi);
    if (r < ne){
      oi[cg2 + r] = myi; ow[cg2 + r] = __uint_as_float(T);
      hist[cg2 + r] = (unsigned)myi; hist[256 + cg2 + r] = T;
    }
  }
  __syncthreads();
  int rbase = (sgn == 0) ? 0 : KPP;
  int lane = t & 63, rw = t >> 6;
  for (int i0 = 0; i0 < K; i0 += 4){
    int r = i0 + rw;
    int idx = (int)hist[r];
    float wv = __uint_as_float(hist[256 + r]);
    float4 vsel;
    if (wv > 0.6f) vsel = ((const float4*)(x + ((long)b*NN + idx)*DD))[lane];
    else vsel = (float4){0.f,0.f,0.f,0.f};
    ((float4*)(node + ((long)b*384 + rbase + r)*DD))[lane] = vsel;
  }
}

// ---------------- row LayerNorm core ----------------
__global__ void rownorm_kernel(const float* __restrict__ X, unsigned short* __restrict__ Y, int rows){
  int w = threadIdx.x >> 6, lane = threadIdx.x & 63;
  long row = (long)blockIdx.x*4 + w;
  if (row >= rows) return;
  const float4* xr = (const float4*)(X + row*DD);
  float4 xv = xr[lane];
  float s = xv.x+xv.y+xv.z+xv.w;
  float q = xv.x*xv.x+xv.y*xv.y+xv.z*xv.z+xv.w*xv.w;
  for (int off = 32; off; off >>= 1){ s += __shfl_xor(s, off); q += __shfl_xor(q, off); }
  float m = s*(1.f/256.f);
  float var = q*(1.f/256.f) - m*m;
  float rinv = rsqrtf(var + 1e-5f);
  ushort4 o;
  o.x = f2bf((xv.x-m)*rinv); o.y = f2bf((xv.y-m)*rinv);
  o.z = f2bf((xv.z-m)*rinv); o.w = f2bf((xv.w-m)*rinv);
  ((ushort4*)(Y + row*DD))[lane] = o;
}

// ---------------- GCN f32 GEMM 64x64 body (device fn, shared passed in) ----------------
struct GP {
  const float* A; long sAb; int lda;
  const float* B; long sBb; int ldb;
  float* C; long sCb; int ldc;
  const int* pidx; const float* pe;
  int M, N, K; float alpha; int flags;
};

__device__ __forceinline__ void gemm64(const GP& p, int bx, int by, int b,
                                       unsigned short* As, unsigned short* Bs){
  int m0 = by*64, n0 = bx*64;
  if (m0 >= p.M || n0 >= p.N) return;
  const float* Ab = p.A + (long)b*p.sAb;
  const float* Bb = p.B + (long)b*p.sBb;
  int t = threadIdx.x;
  int w = t >> 6, lane = t & 63, lrowi = lane & 15, lquad = lane >> 4;
  int wm = w >> 1, wn = w & 1;
  f32x4 acc[2][2];
  #pragma unroll
  for (int i = 0; i < 2; i++)
    #pragma unroll
    for (int j = 0; j < 2; j++) acc[i][j] = (f32x4){0.f,0.f,0.f,0.f};
  int am = t >> 2, akq = t & 3;
  for (int k0 = 0; k0 < p.K; k0 += 32){
    {
      const float4* s4 = (const float4*)(Ab + (long)(m0+am)*p.lda + k0 + akq*8);
      float4 u = s4[0], vv = s4[1];
      unsigned short tmp[8];
      tmp[0]=f2bf(u.x); tmp[1]=f2bf(u.y); tmp[2]=f2bf(u.z); tmp[3]=f2bf(u.w);
      tmp[4]=f2bf(vv.x); tmp[5]=f2bf(vv.y); tmp[6]=f2bf(vv.z); tmp[7]=f2bf(vv.w);
      *(uint4*)(&As[am*40 + akq*8]) = *(uint4*)tmp;
    }
    if (p.flags & FLAG_TRANSB){
      const float4* s4 = (const float4*)(Bb + (long)(n0+am)*p.ldb + k0 + akq*8);
      float4 u = s4[0], vv = s4[1];
      unsigned short tmp[8];
      tmp[0]=f2bf(u.x); tmp[1]=f2bf(u.y); tmp[2]=f2bf(u.z); tmp[3]=f2bf(u.w);
      tmp[4]=f2bf(vv.x); tmp[5]=f2bf(vv.y); tmp[6]=f2bf(vv.z); tmp[7]=f2bf(vv.w);
      *(uint4*)(&Bs[am*40 + akq*8]) = *(uint4*)tmp;
    } else {
      int bn = t & 63, bkb = (t >> 6)*8;
      #pragma unroll
      for (int j = 0; j < 8; j++)
        Bs[bn*40 + bkb + j] = f2bf(Bb[(long)(k0+bkb+j)*p.ldb + n0 + bn]);
    }
    __syncthreads();
    bf16x8 af[2], bfr[2];
    #pragma unroll
    for (int i = 0; i < 2; i++)
      af[i] = *(const bf16x8*)(&As[(wm*32 + i*16 + lrowi)*40 + lquad*8]);
    #pragma unroll
    for (int j = 0; j < 2; j++)
      bfr[j] = *(const bf16x8*)(&Bs[(wn*32 + j*16 + lrowi)*40 + lquad*8]);
    #pragma unroll
    for (int i = 0; i < 2; i++)
      #pragma unroll
      for (int j = 0; j < 2; j++)
        acc[i][j] = __builtin_amdgcn_mfma_f32_16x16x32_bf16(af[i], bfr[j], acc[i][j], 0, 0, 0);
    __syncthreads();
  }
  float* Cb = p.C + (long)b*p.sCb;
  #pragma unroll
  for (int i = 0; i < 2; i++)
    #pragma unroll
    for (int j = 0; j < 2; j++){
      int col = n0 + wn*32 + j*16 + lrowi;
      #pragma unroll
      for (int r = 0; r < 4; r++){
        int row = m0 + wm*32 + i*16 + lquad*4 + r;
        float v = p.alpha*acc[i][j][r];
        if (p.flags & FLAG_RELU) v = fmaxf(v, 0.f);
        if (p.pidx != nullptr){
          int idx = p.pidx[b*512 + row];
          v += p.pe[(long)idx*256 + col];
        }
        Cb[(long)row*p.ldc + col] = v;
      }
    }
}

// ---------------- row softmax (device fn, grid-strided) ----------------
__device__ __forceinline__ void softmax_v(float* A0, int L0, int rpb0, long bs0, int rows0,
                                          float* A1, int L1, int rpb1, long bs1, int rows1,
                                          int vb){
  int w = threadIdx.x >> 6, lane = threadIdx.x & 63;
  long row = (long)vb*4 + w;
  float* A; int L, rpb; long bs;
  if (row < rows0){ A = A0; L = L0; rpb = rpb0; bs = bs0; }
  else { row -= rows0; if (row >= rows1) return; A = A1; L = L1; rpb = rpb1; bs = bs1; }
  int b = (int)(row / rpb), r = (int)(row % rpb);
  float* a = A + (long)b*bs + (long)r*L;
  int e = L >> 6;
  float vals[4]; float mx = -1e30f;
  for (int j = 0; j < e; j++){ vals[j] = a[lane*e+j]; mx = fmaxf(mx, vals[j]); }
  for (int off = 32; off; off >>= 1) mx = fmaxf(mx, __shfl_xor(mx, off));
  float sum = 0.f;
  for (int j = 0; j < e; j++){ vals[j] = expf(vals[j]-mx); sum += vals[j]; }
  for (int off = 32; off; off >>= 1) sum += __shfl_xor(sum, off);
  float rinv = 1.f/sum;
  for (int j = 0; j < e; j++) a[lane*e+j] = vals[j]*rinv;
}

// ---------------- fused GCN: 5 GEMM phases + softmax, hand-rolled device barriers ----------------
// Phase decode verified correct in R6 (passed refcheck); only sync mechanism replaced.
struct GcnArgs {
  GP p1[3]; GP p2[2]; GP p4[2]; GP p5[2]; GP p6[2];
  float* A0; float* A1;
  unsigned int* bar;
};

__global__ __launch_bounds__(256) void gcn_fused(GcnArgs ga){
  __shared__ __align__(16) unsigned short As[64*40];
  __shared__ __align__(16) unsigned short Bs[64*40];
  int id = blockIdx.x;
  // P1: node@adj_w (384), node@w1_p (256), node_n@w1_n (128)  -- 576 blocks
  { int bz = id/24, r = id - bz*24; gemm64(ga.p1[bz>>3], r&3, r>>2, bz&7, As, Bs); }
  gbar(ga.bar+0, 576);
  // P2: adjP/adjN = gA @ node^T  -- 256 blocks
  if (id < 256){ int bz = id>>4; gemm64(ga.p2[bz>>3], id&3, (id>>2)&3, bz&7, As, Bs); }
  gbar(ga.bar+1, 576);
  // P3: softmax rows (3072 rows = 768 virtual 4-row blocks, grid-strided)
  for (int vb = id; vb < 768; vb += 576)
    softmax_v(ga.A0, 256, 256, 65536L, BB*256, ga.A1, 128, 128, 16384L, BB*128, vb);
  gbar(ga.bar+2, 576);
  // P4: relu(adj @ t1)
  if (id < 256){ int bz = id>>4; gemm64(ga.p4[bz>>3], id&3, (id>>2)&3, bz&7, As, Bs); }
  gbar(ga.bar+3, 576);
  // P5: t2 @ w2
  if (id < 256){ int bz = id>>4; gemm64(ga.p5[bz>>3], id&3, (id>>2)&3, bz&7, As, Bs); }
  gbar(ga.bar+4, 576);
  // P6: adj @ t3 + pos_emb[idx]
  if (id < 256){ int bz = id>>4; gemm64(ga.p6[bz>>3], id&3, (id>>2)&3, bz&7, As, Bs); }
}

// ---------------- fast 128x128 bf16 GEMM (K=256), 2-phase counted-vmcnt prefetch ----------------
template<typename OT, bool RES, bool GATE>
__device__ __forceinline__ void gemm128_body(
    const unsigned short* __restrict__ A, long sAb,
    const unsigned short* __restrict__ BT,
    OT* __restrict__ C, long sCb, int ldc,
    const float* __restrict__ R, long sRb,
    const float* __restrict__ bias, const float* __restrict__ gate,
    int bx, int by, int bz,
    unsigned short (&As)[2][4096], unsigned short (&Bs)[2][4096])
{
  int t = threadIdx.x;
  int w = t >> 6, lane = t & 63, lrowi = lane & 15, lquad = lane >> 4;
  int wm = w >> 1, wn = w & 1;
  int m0 = by*128, n0 = bx*128;
  const unsigned short* Ab = A + (long)bz*sAb + (long)m0*256;
  const unsigned short* Bb = BT + (long)n0*256;
  int g0 = t, g1 = 256 + t;
  int row0 = g0 >> 2, kq0 = g0 & 3;
  int row1 = g1 >> 2, kq1 = g1 & 3;
  f32x4 acc[4][4];
  #pragma unroll
  for (int i = 0; i < 4; i++)
    #pragma unroll
    for (int j = 0; j < 4; j++) acc[i][j] = (f32x4){0.f,0.f,0.f,0.f};

  auto stage = [&](int buf, int k0){
    gload16(Ab + (long)row0*256 + k0 + kq0*8, &As[buf][g0*8]);
    gload16(Ab + (long)row1*256 + k0 + kq1*8, &As[buf][g1*8]);
    gload16(Bb + (long)row0*256 + k0 + kq0*8, &Bs[buf][g0*8]);
    gload16(Bb + (long)row1*256 + k0 + kq1*8, &Bs[buf][g1*8]);
  };

  stage(0, 0);
  for (int it = 0; it < 8; it++){
    int cur = it & 1;
    if (it < 7){
      stage(cur ^ 1, (it+1)*32);
      __asm__ volatile("s_waitcnt vmcnt(4)" ::: "memory");   // current tile's 4 loads done
    } else {
      __asm__ volatile("s_waitcnt vmcnt(0)" ::: "memory");
    }
    __builtin_amdgcn_s_barrier();                            // tile visible to all waves
    bf16x8 af[4], bfr[4];
    #pragma unroll
    for (int i = 0; i < 4; i++)
      af[i] = *(const bf16x8*)(&As[cur][((wm*64 + i*16 + lrowi)*4 + lquad)*8]);
    #pragma unroll
    for (int j = 0; j < 4; j++)
      bfr[j] = *(const bf16x8*)(&Bs[cur][((wn*64 + j*16 + lrowi)*4 + lquad)*8]);
    #pragma unroll
    for (int i = 0; i < 4; i++)
      #pragma unroll
      for (int j = 0; j < 4; j++)
        acc[i][j] = __builtin_amdgcn_mfma_f32_16x16x32_bf16(af[i], bfr[j], acc[i][j], 0, 0, 0);
    __asm__ volatile("s_waitcnt lgkmcnt(0)" ::: "memory");   // reads of buf[cur] done
    __builtin_amdgcn_s_barrier();                            // before next iter overwrites buf[cur]
  }
  OT* Cb = C + (long)bz*sCb;
  const float* Rb = RES ? (R + (long)bz*sRb) : nullptr;
  #pragma unroll
  for (int j = 0; j < 4; j++){
    int col = n0 + wn*64 + j*16 + lrowi;
    float bv = bias[col];
    float gv = GATE ? gate[col] : 1.f;
    #pragma unroll
    for (int i = 0; i < 4; i++){
      #pragma unroll
      for (int r = 0; r < 4; r++){
        int row = m0 + wm*64 + i*16 + lquad*4 + r;
        float v = acc[i][j][r] + bv;
        if (GATE) v *= gv;
        if (RES) v += Rb[(long)row*256 + col];
        if constexpr (sizeof(OT) == 4) Cb[(long)row*ldc + col] = v;
        else                           Cb[(long)row*ldc + col] = f2bf(v);
      }
    }
  }
}

template<typename OT, bool RES, bool GATE>
__global__ __launch_bounds__(256) void gemm128(
    const unsigned short* __restrict__ A, long sAb,
    const unsigned short* __restrict__ BT,
    OT* __restrict__ C, long sCb, int ldc,
    const float* __restrict__ R, long sRb,
    const float* __restrict__ bias, const float* __restrict__ gate)
{
  __shared__ __align__(16) unsigned short As[2][4096];
  __shared__ __align__(16) unsigned short Bs[2][4096];
  gemm128_body<OT,RES,GATE>(A, sAb, BT, C, sCb, ldc, R, sRb, bias, gate,
                            blockIdx.x, blockIdx.y, blockIdx.z, As, Bs);
}

// two <ushort,false,false> GEMMs in one launch: set0 = (6,32) blocks, set1 = (2,3)
__global__ __launch_bounds__(256) void gemm128_pair(
    const unsigned short* __restrict__ A0, long sA0, const unsigned short* __restrict__ B0,
    unsigned short* __restrict__ C0, long sC0, int ldc0, const float* __restrict__ bias0,
    const unsigned short* __restrict__ A1, long sA1, const unsigned short* __restrict__ B1,
    unsigned short* __restrict__ C1, long sC1, int ldc1, const float* __restrict__ bias1)
{
  __shared__ __align__(16) unsigned short As[2][4096];
  __shared__ __align__(16) unsigned short Bs[2][4096];
  int x = blockIdx.x, z = blockIdx.z;
  if (x < 192){
    gemm128_body<unsigned short,false,false>(A0, sA0, B0, C0, sC0, ldc0, nullptr, 0, bias0, nullptr,
                                             x % 6, x / 6, z, As, Bs);
  } else {
    int xx = x - 192;
    gemm128_body<unsigned short,false,false>(A1, sA1, B1, C1, sC1, ldc1, nullptr, 0, bias1, nullptr,
                                             xx % 2, xx / 2, z, As, Bs);
  }
}

// ---------------- flash cross-attention, no-max softmax, 64-row K-tile ----------------
template<int NFRAG>
__global__ __launch_bounds__(256) void flash_kernel(
    const unsigned short* __restrict__ Q, long sQb, int ldq,
    const unsigned short* __restrict__ Kt, const unsigned short* __restrict__ Vt,
    long sKb, int ldkv,
    unsigned short* __restrict__ O, long sOb,
    float* __restrict__ Opart, float* __restrict__ Lpart,
    int Nq, int Nk, int nsplit)
{
  __shared__ __align__(16) unsigned short Kl[2][32*72];
  __shared__ __align__(16) unsigned short Vl[2][64*36];
  __shared__ __align__(16) unsigned short Pl[4*NFRAG*16*36];
  int b = blockIdx.z, h = blockIdx.y;
  int nqg = Nq / (64*NFRAG);
  int qg = blockIdx.x % nqg, split = blockIdx.x / nqg;
  int kchunk = Nk / nsplit;
  int kbeg = split*kchunk, kend = kbeg + kchunk;
  int t = threadIdx.x, w = t >> 6, lane = t & 63, lrowi = lane & 15, lquad = lane >> 4;
  int q0 = qg*(64*NFRAG) + w*(16*NFRAG);
  const unsigned short* Qb = Q + (long)b*sQb + h*DHH;
  const unsigned short* Kb = Kt + (long)b*sKb + h*DHH;
  const unsigned short* Vb = Vt + (long)b*sKb + h*DHH;
  bf16x8 qa[NFRAG][2];
  #pragma unroll
  for (int f = 0; f < NFRAG; f++)
    #pragma unroll
    for (int kt = 0; kt < 2; kt++)
      qa[f][kt] = *(const bf16x8*)(Qb + (long)(q0 + f*16 + lrowi)*ldq + kt*32 + lquad*8);

  f32x4 o[NFRAG][4];
  float psum[NFRAG][4];
  #pragma unroll
  for (int f = 0; f < NFRAG; f++)
    #pragma unroll
    for (int cj = 0; cj < 4; cj++){
      o[f][cj] = (f32x4){0.f,0.f,0.f,0.f};
      psum[f][cj] = 0.f;
    }
  int skq = t >> 3, sdq = (t & 7)*8;
  int skrow = ((skq & 1) << 4) | (skq >> 1);
  int vkq = t & 31, vdq = (t >> 5)*8;
  unsigned short* Pw = &Pl[w*(NFRAG*16*36)];

  for (int kt0 = kbeg; kt0 < kend; kt0 += 64){
    {
      uint4 k0v = *(const uint4*)(Kb + (long)(kt0+skq)*ldkv + sdq);
      uint4 v0v = *(const uint4*)(Vb + (long)(kt0+vkq)*ldkv + vdq);
      uint4 k1v = *(const uint4*)(Kb + (long)(kt0+32+skq)*ldkv + sdq);
      uint4 v1v = *(const uint4*)(Vb + (long)(kt0+32+vkq)*ldkv + vdq);
      *(uint4*)(&Kl[0][skrow*72 + sdq]) = k0v;
      const unsigned short* vp0 = (const unsigned short*)&v0v;
      #pragma unroll
      for (int j = 0; j < 8; j++) Vl[0][(vdq+j)*36 + vkq] = vp0[j];
      *(uint4*)(&Kl[1][skrow*72 + sdq]) = k1v;
      const unsigned short* vp1 = (const unsigned short*)&v1v;
      #pragma unroll
      for (int j = 0; j < 8; j++) Vl[1][(vdq+j)*36 + vkq] = vp1[j];
    }
    __syncthreads();
    #pragma unroll
    for (int s = 0; s < 2; s++){
      bf16x8 kb0 = *(const bf16x8*)(&Kl[s][(0*16+lrowi)*72 + lquad*8]);
      bf16x8 kb1 = *(const bf16x8*)(&Kl[s][(0*16+lrowi)*72 + 32 + lquad*8]);
      bf16x8 kb2 = *(const bf16x8*)(&Kl[s][(1*16+lrowi)*72 + lquad*8]);
      bf16x8 kb3 = *(const bf16x8*)(&Kl[s][(1*16+lrowi)*72 + 32 + lquad*8]);
      union { bf16x8 v8; bf16x4 v4[2]; } vbu[4];
      #pragma unroll
      for (int cj = 0; cj < 4; cj++){
        const unsigned short* vb = &Vl[s][(cj*16+lrowi)*36 + lquad*8];
        vbu[cj].v4[0] = *(const bf16x4*)vb;
        vbu[cj].v4[1] = *(const bf16x4*)(vb + 4);
      }
      #pragma unroll
      for (int f = 0; f < NFRAG; f++){
        f32x4 S0 = (f32x4){0.f,0.f,0.f,0.f}, S1 = (f32x4){0.f,0.f,0.f,0.f};
        __builtin_amdgcn_s_setprio(1);
        S0 = __builtin_amdgcn_mfma_f32_16x16x32_bf16(qa[f][0], kb0, S0, 0, 0, 0);
        S0 = __builtin_amdgcn_mfma_f32_16x16x32_bf16(qa[f][1], kb1, S0, 0, 0, 0);
        S1 = __builtin_amdgcn_mfma_f32_16x16x32_bf16(qa[f][0], kb2, S1, 0, 0, 0);
        S1 = __builtin_amdgcn_mfma_f32_16x16x32_bf16(qa[f][1], kb3, S1, 0, 0, 0);
        __builtin_amdgcn_s_setprio(0);
        unsigned short* Pf = Pw + f*(16*36);
        #pragma unroll
        for (int r = 0; r < 4; r++){
          float p0 = exp2f(S0[r]);           // even k-col (orig 2*lrowi)
          float p1 = exp2f(S1[r]);           // odd  k-col (orig 2*lrowi+1)
          psum[f][r] += p0 + p1;
          unsigned int pk;
          asm("v_cvt_pk_bf16_f32 %0, %1, %2" : "=v"(pk) : "v"(p0), "v"(p1));
          *(unsigned int*)(&Pf[(lquad*4+r)*36 + 2*lrowi]) = pk;
        }
      }
      __asm__ volatile("s_waitcnt lgkmcnt(0)" ::: "memory");
      #pragma unroll
      for (int f = 0; f < NFRAG; f++){
        const unsigned short* pp = &Pw[f*(16*36) + lrowi*36 + lquad*8];
        union { bf16x8 v8; bf16x4 v4[2]; } pa;
        pa.v4[0] = *(const bf16x4*)pp;
        pa.v4[1] = *(const bf16x4*)(pp + 4);
        __builtin_amdgcn_s_setprio(1);
        #pragma unroll
        for (int cj = 0; cj < 4; cj++)
          o[f][cj] = __builtin_amdgcn_mfma_f32_16x16x32_bf16(pa.v8, vbu[cj].v8, o[f][cj], 0, 0, 0);
        __builtin_amdgcn_s_setprio(0);
      }
    }
    __syncthreads();
  }
  float lsum[NFRAG][4];
  #pragma unroll
  for (int f = 0; f < NFRAG; f++)
    #pragma unroll
    for (int r = 0; r < 4; r++){
      float s = psum[f][r];
      #pragma unroll
      for (int off = 1; off < 16; off <<= 1) s += __shfl_xor(s, off);
      lsum[f][r] = s;
    }
  if (nsplit > 1){
    int p = (b*HH + h)*nsplit + split;
    float* Op = Opart + (long)p*Nq*DHH;
    #pragma unroll
    for (int f = 0; f < NFRAG; f++)
      #pragma unroll
      for (int r = 0; r < 4; r++){
        int row = q0 + f*16 + lquad*4 + r;
        #pragma unroll
        for (int cj = 0; cj < 4; cj++)
          Op[(long)row*DHH + cj*16 + lrowi] = o[f][cj][r];
        if (lrowi == 0) Lpart[(long)p*Nq + row] = lsum[f][r];
      }
  } else {
    unsigned short* Ob = O + (long)b*sOb + h*DHH;
    #pragma unroll
    for (int f = 0; f < NFRAG; f++)
      #pragma unroll
      for (int r = 0; r < 4; r++){
        float rl = 1.f/lsum[f][r];
        int row = q0 + f*16 + lquad*4 + r;
        #pragma unroll
        for (int cj = 0; cj < 4; cj++)
          Ob[(long)row*DD + cj*16 + lrowi] = f2bf(o[f][cj][r]*rl);
      }
  }
}

// ---------------- flash split combine ----------------
__global__ void flash_combine(const float* __restrict__ Opart, const float* __restrict__ Lpart,
                              unsigned short* __restrict__ O, long sOb, int Nq, int nsplit){
  int gr = blockIdx.x*4 + (threadIdx.x >> 6);
  int d = threadIdx.x & 63;
  int bh = gr / Nq, row = gr % Nq;
  float accO = 0.f, accL = 0.f;
  for (int s = 0; s < nsplit; s++){
    long p = (long)bh*nsplit + s;
    accL += Lpart[p*Nq + row];
    accO += Opart[(p*Nq + row)*DHH + d];
  }
  int b = bh / HH, h = bh % HH;
  O[(long)b*sOb + (long)row*DD + h*DHH + d] = f2bf(accO/accL);
}

// ---------------- host ----------------
extern "C" void kernel_launch(void* const* d_in, const int* in_sizes, int n_in,
                              void* d_out, int out_size, void* d_ws, size_t ws_size,
                              hipStream_t stream) {
  (void)in_sizes; (void)n_in; (void)out_size; (void)ws_size;
  const float* x        = (const float*)d_in[0];
  const int*   mask     = (const int*)d_in[1];
  const float* pos_emb  = (const float*)d_in[2];
  const float* sim_p_w  = (const float*)d_in[3];
  const float* sim_p_b  = (const float*)d_in[4];
  const float* sim_n_w  = (const float*)d_in[5];
  const float* sim_n_b  = (const float*)d_in[6];
  const float* adj_w    = (const float*)d_in[7];
  const float* gnn_p_w1 = (const float*)d_in[8];
  const float* gnn_p_w2 = (const float*)d_in[9];
  const float* gnn_n_w1 = (const float*)d_in[10];
  const float* gnn_n_w2 = (const float*)d_in[11];
  const float* ln1_g = (const float*)d_in[12]; const float* ln1_b = (const float*)d_in[13];
  const float* ln2_g = (const float*)d_in[14]; const float* ln2_b = (const float*)d_in[15];
  const float* ln3_g = (const float*)d_in[16]; const float* ln3_b = (const float*)d_in[17];
  const float* ln4_g = (const float*)d_in[18]; const float* ln4_b = (const float*)d_in[19];
  const float* ln5_g = (const float*)d_in[20]; const float* ln5_b = (const float*)d_in[21];
  const float* i2q_wq = (const float*)d_in[22];
  const float* i2q_wk = (const float*)d_in[23];
  const float* i2q_wv = (const float*)d_in[24];
  const float* i2q_wo = (const float*)d_in[25];
  const float* q2i_wq = (const float*)d_in[26];
  const float* q2i_wk = (const float*)d_in[27];
  const float* q2i_wv = (const float*)d_in[28];
  const float* q2i_wo = (const float*)d_in[29];
  const float* i2q_bo = (const float*)d_in[30];
  const float* q2i_bo = (const float*)d_in[31];
  const float* mlp_w  = (const float*)d_in[32];
  const float* mlp_b  = (const float*)d_in[33];
  const float* g_i2t  = (const float*)d_in[34];
  const float* g_t2i  = (const float*)d_in[35];

  float* out  = (float*)d_out;
  float* simP = out + (size_t)BB*NN*DD;
  float* simN = simP + (size_t)BB*NN;

  char* w8 = (char*)d_ws;
  size_t off = 0;
  auto take = [&](size_t bytes)->void*{
    void* p = (void*)(w8 + off);
    off += (bytes + 255) & ~(size_t)255;
    return p;
  };
  float* part   = (float*)take((size_t)BB*SCH*2*DD*4);
  float* pcnt   = (float*)take((size_t)BB*SCH*2*4);
  float* vvec   = (float*)take((size_t)BB*2*DD*4);
  float* cscal  = (float*)take((size_t)BB*2*4);
  int*   idxb   = (int*)take((size_t)BB*2*256*4);
  float* wb     = (float*)take((size_t)BB*2*256*4);
  float* node   = (float*)take((size_t)BB*384*DD*4);
  float* gA     = (float*)take((size_t)BB*384*DD*4);   // also t3
  float* gadjP  = (float*)take((size_t)BB*256*256*4);
  float* gadjN  = (float*)take((size_t)BB*128*128*4);
  float* query  = (float*)take((size_t)BB*384*DD*4);   // also t1
  float* query2 = (float*)take((size_t)BB*384*DD*4);   // also t2
  unsigned short* xhatq  = (unsigned short*)take((size_t)BB*384*DD*2);
  unsigned short* qh     = (unsigned short*)take((size_t)BB*384*DD*2);
  unsigned short* attnZ  = (unsigned short*)take((size_t)BB*384*DD*2);
  unsigned short* xhatq2 = (unsigned short*)take((size_t)BB*384*DD*2);
  unsigned short* kv2    = (unsigned short*)take((size_t)BB*384*512*2);
  unsigned short* xhat   = (unsigned short*)take((size_t)BB*NN*DD*2);
  unsigned short* kvq    = (unsigned short*)take((size_t)BB*NN*768*2);
  float* featb2 = (float*)take((size_t)BB*NN*DD*4);
  float* Lpart  = (float*)take((size_t)BB*HH*8*384*4);
  unsigned short* wTq1  = (unsigned short*)take((size_t)65536*2);
  unsigned short* wTbig = (unsigned short*)take((size_t)3*65536*2);
  unsigned short* wTkv2 = (unsigned short*)take((size_t)2*65536*2);
  unsigned short* wTmlp = (unsigned short*)take((size_t)65536*2);
  unsigned short* wTo1  = (unsigned short*)take((size_t)65536*2);
  unsigned short* wTo2  = (unsigned short*)take((size_t)65536*2);
  float* biasQ1  = (float*)take(256*4);
  float* biasBig = (float*)take(768*4);
  float* biasKV2 = (float*)take(512*4);
  float* biasMlp = (float*)take(256*4);
  unsigned int* bar = (unsigned int*)take(256);
  // overlays (disjoint lifetimes):
  float* t1 = query;
  float* t2 = query2;
  float* t3 = gA;
  unsigned short* attn2 = xhat;
  unsigned short* xhat5 = kvq;
  float* Opart = featb2;

  const long sQ  = 384L*DD;
  const long sX  = (long)NN*DD;
  const float* NF = nullptr;

  // softmax scale (1/sqrt(dh)) * log2(e), folded into the Q projections
  const float QS = 0.125f * 1.44269504088896f;

  // ---- merged weight folds + stats_part (independent; one launch) ----
  FoldArgs fa;
  fa.W[0]=i2q_wq; fa.g[0]=ln1_g; fa.BT[0]=wTq1;            fa.sc[0]=QS;
  fa.W[1]=i2q_wk; fa.g[1]=ln2_g; fa.BT[1]=wTbig;           fa.sc[1]=1.f;
  fa.W[2]=i2q_wv; fa.g[2]=ln2_g; fa.BT[2]=wTbig + 256*256; fa.sc[2]=1.f;
  fa.W[3]=q2i_wq; fa.g[3]=ln3_g; fa.BT[3]=wTbig + 512*256; fa.sc[3]=QS;
  fa.W[4]=q2i_wk; fa.g[4]=ln4_g; fa.BT[4]=wTkv2;           fa.sc[4]=1.f;
  fa.W[5]=q2i_wv; fa.g[5]=ln4_g; fa.BT[5]=wTkv2 + 256*256; fa.sc[5]=1.f;
  fa.W[6]=mlp_w;  fa.g[6]=ln5_g; fa.BT[6]=wTmlp;           fa.sc[6]=1.f;
  fa.W[7]=i2q_wo; fa.g[7]=nullptr; fa.BT[7]=wTo1;          fa.sc[7]=1.f;
  fa.W[8]=q2i_wo; fa.g[8]=nullptr; fa.BT[8]=wTo2;          fa.sc[8]=1.f;
  BiasArgs ba;
  ba.W[0]=i2q_wq; ba.b[0]=ln1_b; ba.addb[0]=nullptr; ba.out[0]=biasQ1;     ba.sc[0]=QS;
  ba.W[1]=i2q_wk; ba.b[1]=ln2_b; ba.addb[1]=nullptr; ba.out[1]=biasBig;    ba.sc[1]=1.f;
  ba.W[2]=i2q_wv; ba.b[2]=ln2_b; ba.addb[2]=nullptr; ba.out[2]=biasBig+256; ba.sc[2]=1.f;
  ba.W[3]=q2i_wq; ba.b[3]=ln3_b; ba.addb[3]=nullptr; ba.out[3]=biasBig+512; ba.sc[3]=QS;
  ba.W[4]=q2i_wk; ba.b[4]=ln4_b; ba.addb[4]=nullptr; ba.out[4]=biasKV2;    ba.sc[4]=1.f;
  ba.W[5]=q2i_wv; ba.b[5]=ln4_b; ba.addb[5]=nullptr; ba.out[5]=biasKV2+256; ba.sc[5]=1.f;
  ba.W[6]=mlp_w;  ba.b[6]=ln5_b; ba.addb[6]=mlp_b;   ba.out[6]=biasMlp;    ba.sc[6]=1.f;
  fold_stats<<<dim3(64,18), 256, 0, stream>>>(fa, ba, x, mask, part, pcnt);

  // ---- stats reduce + matvec + cscal (one launch) / sims / topk+gather ----
  stats_sim<<<dim3(9, BB), 256, 0, stream>>>(part, pcnt, sim_p_w, sim_n_w,
                                             sim_p_b, sim_n_b, vvec, cscal);
  sim_norm_kernel<<<dim3(NN/4, BB), 256, 0, stream>>>(x, vvec, cscal, simP, simN, xhat);
  topk_radix<<<2*BB, 256, 0, stream>>>(simP, simN, x, idxb, wb, node);

  // ---- GCN (pos/neg paired) — single kernel, hand-rolled device barriers ----
  GcnArgs ga;
  ga.p1[0] = { node, 384L*DD, 256, adj_w, 0, 256, gA, 384L*DD, 256, nullptr, nullptr, 384, 256, 256, 1.f, 0 };
  ga.p1[1] = { node, 384L*DD, 256, gnn_p_w1, 0, 256, t1, 384L*DD, 256, nullptr, nullptr, 256, 256, 256, 1.f, 0 };
  ga.p1[2] = { node + 256L*DD, 384L*DD, 256, gnn_n_w1, 0, 256, t1 + 256L*DD, 384L*DD, 256, nullptr, nullptr, 128, 256, 256, 1.f, 0 };
  ga.p2[0] = { gA, 384L*DD, 256, node, 384L*DD, 256, gadjP, 65536L, 256, nullptr, nullptr, 256, 256, 256, 0.0625f, FLAG_TRANSB };
  ga.p2[1] = { gA + 256L*DD, 384L*DD, 256, node + 256L*DD, 384L*DD, 256, gadjN, 16384L, 128, nullptr, nullptr, 128, 128, 256, 0.0625f, FLAG_TRANSB };
  ga.p4[0] = { gadjP, 65536L, 256, t1, 384L*DD, 256, t2, 384L*DD, 256, nullptr, nullptr, 256, 256, 256, 1.f, FLAG_RELU };
  ga.p4[1] = { gadjN, 16384L, 128, t1 + 256L*DD, 384L*DD, 256, t2 + 256L*DD, 384L*DD, 256, nullptr, nullptr, 128, 256, 128, 1.f, FLAG_RELU };
  ga.p5[0] = { t2, 384L*DD, 256, gnn_p_w2, 0, 256, t3, 384L*DD, 256, nullptr, nullptr, 256, 256, 256, 1.f, 0 };
  ga.p5[1] = { t2 + 256L*DD, 384L*DD, 256, gnn_n_w2, 0, 256, t3 + 256L*DD, 384L*DD, 256, nullptr, nullptr, 128, 256, 256, 1.f, 0 };
  ga.p6[0] = { gadjP, 65536L, 256, t3, 384L*DD, 256, query, 384L*DD, 256, idxb, pos_emb, 256, 256, 256, 1.f, 0 };
  ga.p6[1] = { gadjN, 16384L, 128, t3 + 256L*DD, 384L*DD, 256, query + 256L*DD, 384L*DD, 256, idxb + 256, pos_emb, 128, 256, 128, 1.f, 0 };
  ga.A0 = gadjP; ga.A1 = gadjN;
  ga.bar = bar;
  hipMemsetAsync(bar, 0, 256, stream);
  gcn_fused<<<576, 256, 0, stream>>>(ga);

  // ---- LN core of query ----
  rownorm_kernel<<<BB*384/4, 256, 0, stream>>>(query, xhatq, BB*384);

  // (a)+(b) merged: qh = xhatq @ wq' + b'  and  [kh|vh|qh2] = xhat @ [wk'|wv'|wq2'] + b'
  gemm128_pair<<<dim3(198,1,BB),256,0,stream>>>(
      xhat, sX, wTbig, kvq, (long)NN*768, 768, biasBig,
      xhatq, sQ, wTq1, qh, sQ, 256, biasQ1);
  // i2q flash (NFRAG=3, K-split 8) + combine
  flash_kernel<3><<<dim3(2*8, HH, BB), 256, 0, stream>>>(
      qh, sQ, 256, kvq, kvq + 256, (long)NN*768, 768,
      attnZ, sQ, Opart, Lpart, 384, NN, 8);
  flash_combine<<<BB*HH*384/4, 256, 0, stream>>>(Opart, Lpart, attnZ, sQ, 384, 8);
  // (c) query2 = query + g_i2t .* (attnZ @ wo + bo)
  gemm128<float,true,true><<<dim3(2,3,BB),256,0,stream>>>(
      attnZ, sQ, wTo1, query2, sQ, 256, query, sQ, i2q_bo, g_i2t);

  // ---- q2i ----
  rownorm_kernel<<<BB*384/4, 256, 0, stream>>>(query2, xhatq2, BB*384);
  // (d) [k2|v2] = xhatq2 @ [wk2'|wv2'] + b'
  gemm128<unsigned short,false,false><<<dim3(4,3,BB),256,0,stream>>>(
      xhatq2, sQ, wTkv2, kv2, 384L*512, 512, NF, 0, biasKV2, NF);
  flash_kernel<2><<<dim3(32, HH, BB), 256, 0, stream>>>(
      kvq + 512, (long)NN*768, 768, kv2, kv2 + 256, 384L*512, 512,
      attn2, sX, nullptr, nullptr, NN, 384, 1);
  // (e) featb2 = x + g_t2i .* (attn2 @ wo + bo)
  gemm128<float,true,true><<<dim3(2,32,BB),256,0,stream>>>(
      attn2, sX, wTo2, featb2, sX, 256, x, sX, q2i_bo, g_t2i);

  // ---- final MLP ----
  rownorm_kernel<<<BB*NN/4, 256, 0, stream>>>(featb2, xhat5, BB*NN);
  gemm128<float,true,false><<<dim3(2,32,BB),256,0,stream>>>(
      xhat5, sX, wTmlp, out, sX, 256, featb2, sX, biasMlp, NF);
}

// Round 8
// 445.901 us; speedup vs baseline: 2.1482x; 2.1482x over previous
//
#include <hip/hip_runtime.h>

#define BB 8
#define NN 4096
#define DD 256
#define HH 4
#define DHH 64
#define KPP 256
#define KNN 128
#define SCH 64   // stats chunks per batch (64 rows each)

typedef float f32x4 __attribute__((ext_vector_type(4)));
typedef short bf16x8 __attribute__((ext_vector_type(8)));
typedef short bf16x4 __attribute__((ext_vector_type(4)));

#define FLAG_TRANSB 1
#define FLAG_RELU   2

__device__ __forceinline__ float bf2f(unsigned short u){
  union { unsigned int i; float f; } v; v.i = ((unsigned int)u) << 16; return v.f;
}
__device__ __forceinline__ unsigned short f2bf(float f){
  union { float f; unsigned int i; } v; v.f = f;
  return (unsigned short)((v.i + 0x7FFFu + ((v.i >> 16) & 1u)) >> 16);
}
__device__ __forceinline__ void gload16(const void* g, void* l){
  __builtin_amdgcn_global_load_lds((const __attribute__((address_space(1))) void*)g,
                                   (__attribute__((address_space(3))) void*)l, 16, 0, 0);
}

// ---------------- merged fold_all + stats_part (independent work, one launch) ----------------
struct FoldArgs { const float* W[9]; const float* g[9]; unsigned short* BT[9]; float sc[9]; };
struct BiasArgs { const float* W[7]; const float* b[7]; const float* addb[7]; float* out[7]; float sc[7]; };

__global__ __launch_bounds__(256) void fold_stats(FoldArgs fa, BiasArgs ba,
                                                  const float* __restrict__ x,
                                                  const int* __restrict__ mask,
                                                  float* __restrict__ part,
                                                  float* __restrict__ pcnt){
  __shared__ __align__(16) char smem[16640];
  int t = threadIdx.x;
  int by = blockIdx.y;
  if (by < 9){
    if (blockIdx.x >= 16) return;
    float (*T)[65] = (float(*)[65])smem;
    int m = by, tile = blockIdx.x;
    const float* W = fa.W[m]; const float* g = fa.g[m]; unsigned short* BT = fa.BT[m];
    float sc = fa.sc[m];
    int tn = (tile & 3)*64, tk = (tile >> 2)*64;
    #pragma unroll 4
    for (int p = 0; p < 16; p++){
      int kl = p*4 + (t >> 6), nl = t & 63;
      float v = W[(long)(tk+kl)*256 + tn + nl];
      if (g) v *= g[tk+kl];
      T[kl][nl] = v * sc;
    }
    __syncthreads();
    #pragma unroll 4
    for (int p = 0; p < 16; p++){
      int nl = p*4 + (t >> 6), kl = t & 63;
      BT[(long)(tn+nl)*256 + tk + kl] = f2bf(T[kl][nl]);
    }
  } else if (by == 9){
    if (blockIdx.x >= 7) return;
    int m = blockIdx.x, n = t;
    const float* W = ba.W[m]; const float* b = ba.b[m];
    float s = (ba.addb[m] != nullptr) ? ba.addb[m][n] : 0.f;
    for (int k = 0; k < 256; k++) s += b[k]*W[(long)k*256+n];
    ba.out[m][n] = s * ba.sc[m];
  } else {
    int b = by - 10, c = blockIdx.x;
    int w = t >> 6, lane = t & 63;
    const int R = NN / SCH;           // 64 rows per chunk
    int n0 = c * R;
    const float* xb = x + ((long)b*NN + n0)*DD;
    const int* mb = mask + (long)b*NN + n0;
    float4 sp = {0.f,0.f,0.f,0.f}, sn = {0.f,0.f,0.f,0.f};
    int cp = 0, cn = 0;
    #pragma unroll 4
    for (int r = w; r < R; r += 4){
      int mv = mb[r];
      float4 v = ((const float4*)(xb + (long)r*DD))[lane];
      if (mv == 1){ sp.x += v.x; sp.y += v.y; sp.z += v.z; sp.w += v.w; cp++; }
      else if (mv == -1){ sn.x += v.x; sn.y += v.y; sn.z += v.z; sn.w += v.w; cn++; }
    }
    float (*red)[4][256] = (float(*)[4][256])smem;
    int* cnt = (int*)(smem + 8192);
    ((float4*)&red[0][w][0])[lane] = sp;
    ((float4*)&red[1][w][0])[lane] = sn;
    if (lane == 0){ cnt[w] = cp; cnt[4+w] = cn; }
    __syncthreads();
    float s0 = red[0][0][t]+red[0][1][t]+red[0][2][t]+red[0][3][t];
    float s1 = red[1][0][t]+red[1][1][t]+red[1][2][t]+red[1][3][t];
    part[(((long)(b*SCH+c)*2+0)*DD)+t] = s0;
    part[(((long)(b*SCH+c)*2+1)*DD)+t] = s1;
    if (t == 0){
      pcnt[(b*SCH+c)*2+0] = (float)(cnt[0]+cnt[1]+cnt[2]+cnt[3]);
      pcnt[(b*SCH+c)*2+1] = (float)(cnt[4]+cnt[5]+cnt[6]+cnt[7]);
    }
  }
}

// ---------------- merged stats reduce + matvec + cscal (one launch) ----------------
__global__ void stats_sim(const float* __restrict__ part, const float* __restrict__ pcnt,
                          const float* __restrict__ Wp, const float* __restrict__ Wn,
                          const float* __restrict__ bp, const float* __restrict__ bn,
                          float* __restrict__ vvec, float* __restrict__ cscal){
  int c = blockIdx.x, b = blockIdx.y, t = threadIdx.x;
  __shared__ float qp[256], qn[256], red[256];
  {
    float sp=0.f, sn=0.f, cp=0.f, cn=0.f;
    for (int ch = 0; ch < SCH; ch++){
      sp += part[(((long)(b*SCH+ch)*2+0)*DD)+t];
      sn += part[(((long)(b*SCH+ch)*2+1)*DD)+t];
      cp += pcnt[(b*SCH+ch)*2+0];
      cn += pcnt[(b*SCH+ch)*2+1];
    }
    qp[t] = sp / (cp + 1e-6f);
    qn[t] = sn / (cn + 1e-6f);
  }
  __syncthreads();
  if (c < 8){
    int row = c*32 + (t >> 3);
    int seg = (t & 7)*32;
    const float* wp = Wp + (long)row*DD + seg;
    const float* wn = Wn + (long)row*DD + seg;
    float ap = 0.f, an = 0.f;
    #pragma unroll 8
    for (int j = 0; j < 32; j++){ ap += wp[j]*qp[seg+j]; an += wn[j]*qn[seg+j]; }
    #pragma unroll
    for (int off = 1; off < 8; off <<= 1){ ap += __shfl_xor(ap, off); an += __shfl_xor(an, off); }
    if ((t & 7) == 0){
      vvec[(long)(b*2+0)*DD + row] = ap;
      vvec[(long)(b*2+1)*DD + row] = an;
    }
  } else {
    red[t] = bp[t]*qp[t];
    __syncthreads();
    for (int s = 128; s > 0; s >>= 1){ if (t < s) red[t] += red[t+s]; __syncthreads(); }
    if (t == 0) cscal[b*2+0] = red[0];
    __syncthreads();
    red[t] = bn[t]*qn[t];
    __syncthreads();
    for (int s = 128; s > 0; s >>= 1){ if (t < s) red[t] += red[t+s]; __syncthreads(); }
    if (t == 0) cscal[b*2+1] = red[0];
  }
}

// ---------------- fused sims + LN-core of x ----------------
__global__ void sim_norm_kernel(const float* __restrict__ x, const float* __restrict__ vvec,
                                const float* __restrict__ cscal,
                                float* __restrict__ simP, float* __restrict__ simN,
                                unsigned short* __restrict__ xhat){
  int b = blockIdx.y;
  int w = threadIdx.x >> 6, lane = threadIdx.x & 63;
  int n = blockIdx.x*4 + w;
  long row = (long)b*NN + n;
  const float4* xr = (const float4*)(x + row*DD);
  float4 xv = xr[lane];
  float4 a = ((const float4*)(vvec + (long)(b*2+0)*DD))[lane];
  float4 c = ((const float4*)(vvec + (long)(b*2+1)*DD))[lane];
  float sp = xv.x*a.x + xv.y*a.y + xv.z*a.z + xv.w*a.w;
  float sn = xv.x*c.x + xv.y*c.y + xv.z*c.z + xv.w*c.w;
  float s  = xv.x+xv.y+xv.z+xv.w;
  float q  = xv.x*xv.x+xv.y*xv.y+xv.z*xv.z+xv.w*xv.w;
  for (int off = 32; off; off >>= 1){
    sp += __shfl_xor(sp, off); sn += __shfl_xor(sn, off);
    s  += __shfl_xor(s, off);  q  += __shfl_xor(q, off);
  }
  float m = s*(1.f/256.f);
  float var = q*(1.f/256.f) - m*m;
  float rinv = rsqrtf(var + 1e-5f);
  ushort4 o;
  o.x = f2bf((xv.x-m)*rinv); o.y = f2bf((xv.y-m)*rinv);
  o.z = f2bf((xv.z-m)*rinv); o.w = f2bf((xv.w-m)*rinv);
  ((ushort4*)(xhat + row*DD))[lane] = o;
  if (lane == 0){
    float zp = sp + cscal[b*2+0], zn = sn + cscal[b*2+1];
    simP[row] = 1.f/(1.f+expf(-zp));
    simN[row] = 1.f/(1.f+expf(-zn));
  }
}

// ---------------- top-k (3-pass radix, parallel scans) + fused node gather ----------------
__global__ __launch_bounds__(256) void topk_radix(const float* __restrict__ simP,
                                                  const float* __restrict__ simN,
                                                  const float* __restrict__ x,
                                                  int* __restrict__ idxb, float* __restrict__ wb,
                                                  float* __restrict__ node){
  __shared__ unsigned int vals[4096];
  __shared__ unsigned int hist[4096];
  __shared__ unsigned short eql[4096];
  __shared__ unsigned int tsum[256];
  __shared__ unsigned int sB, sRem, sCG, sCnt, sEq;
  int id = blockIdx.x; int sgn = id & 1, b = id >> 1;
  int K = (sgn == 0) ? KPP : KNN;
  const float* s = (sgn == 0 ? simP : simN) + (long)b*NN;
  int t = threadIdx.x;
  if (t == 0){ sCG = 0; sCnt = 0; sEq = 0; }
  for (int i = t; i < 4096; i += 256){ vals[i] = __float_as_uint(s[i]); hist[i] = 0; }
  __syncthreads();

  auto find_thresh = [&](int NB, unsigned need){
    int per = NB >> 8;
    int base = t*per;
    unsigned local = 0;
    for (int j = 0; j < per; j++) local += hist[base+j];
    tsum[t] = local;
    __syncthreads();
    #pragma unroll
    for (int st = 1; st < 256; st <<= 1){
      unsigned v = (t + st < 256) ? tsum[t+st] : 0u;
      __syncthreads();
      tsum[t] += v;
      __syncthreads();
    }
    unsigned after = (t < 255) ? tsum[t+1] : 0u;
    if (after < need && after + local >= need){
      unsigned c = after;
      for (int j = per-1; j >= 0; j--){
        unsigned h = hist[base+j];
        c += h;
        if (c >= need){
          sB = (unsigned)(base+j);
          sRem = need - (c - h);
          atomicAdd(&sCG, c - h);
          break;
        }
      }
    }
    __syncthreads();
  };

  for (int i = t; i < 4096; i += 256) atomicAdd(&hist[vals[i] >> 20], 1u);
  __syncthreads();
  find_thresh(4096, (unsigned)K);
  unsigned B1 = sB, rem1 = sRem;
  __syncthreads();
  for (int i = t; i < 4096; i += 256) hist[i] = 0;
  __syncthreads();
  for (int i = t; i < 4096; i += 256){
    unsigned v = vals[i];
    if ((v >> 20) == B1) atomicAdd(&hist[(v >> 8) & 0xFFFu], 1u);
  }
  __syncthreads();
  find_thresh(4096, rem1);
  unsigned B2 = sB, rem2 = sRem;
  unsigned pre = (B1 << 12) | B2;
  __syncthreads();
  hist[t] = 0;
  __syncthreads();
  for (int i = t; i < 4096; i += 256){
    unsigned v = vals[i];
    if ((v >> 8) == pre) atomicAdd(&hist[v & 0xFFu], 1u);
  }
  __syncthreads();
  find_thresh(256, rem2);
  unsigned T = (pre << 8) | sB;
  unsigned cg2 = sCG;
  __syncthreads();
  hist[t] = 0;
  __syncthreads();

  int* oi = idxb + (long)id*256;
  float* ow = wb + (long)id*256;
  for (int i = t; i < 4096; i += 256){
    unsigned v = vals[i];
    if (v > T){
      unsigned p = atomicAdd(&sCnt, 1u);
      oi[p] = i; ow[p] = __uint_as_float(v);
      hist[p] = (unsigned)i; hist[256+p] = v;
    }
    else if (v == T){ unsigned e = atomicAdd(&sEq, 1u); eql[e] = (unsigned short)i; }
  }
  __syncthreads();
  int ne = K - (int)cg2;
  int eqn = (int)sEq;
  for (int e = t; e < eqn; e += 256){
    int myi = eql[e]; int r = 0;
    for (int e2 = 0; e2 < eqn; e2++) r += (eql[e2] < myi);
    if (r < ne){
      oi[cg2 + r] = myi; ow[cg2 + r] = __uint_as_float(T);
      hist[cg2 + r] = (unsigned)myi; hist[256 + cg2 + r] = T;
    }
  }
  __syncthreads();
  int rbase = (sgn == 0) ? 0 : KPP;
  int lane = t & 63, rw = t >> 6;
  for (int i0 = 0; i0 < K; i0 += 4){
    int r = i0 + rw;
    int idx = (int)hist[r];
    float wv = __uint_as_float(hist[256 + r]);
    float4 vsel;
    if (wv > 0.6f) vsel = ((const float4*)(x + ((long)b*NN + idx)*DD))[lane];
    else vsel = (float4){0.f,0.f,0.f,0.f};
    ((float4*)(node + ((long)b*384 + rbase + r)*DD))[lane] = vsel;
  }
}

// ---------------- dual row softmax ----------------
__global__ void softmax_dual(float* __restrict__ A0, int L0, int rpb0, long bs0, int rows0,
                             float* __restrict__ A1, int L1, int rpb1, long bs1, int rows1){
  int w = threadIdx.x >> 6, lane = threadIdx.x & 63;
  long row = (long)blockIdx.x*4 + w;
  float* A; int L, rpb; long bs;
  if (row < rows0){ A = A0; L = L0; rpb = rpb0; bs = bs0; }
  else { row -= rows0; if (row >= rows1) return; A = A1; L = L1; rpb = rpb1; bs = bs1; }
  int b = (int)(row / rpb), r = (int)(row % rpb);
  float* a = A + (long)b*bs + (long)r*L;
  int e = L >> 6;
  float vals[4]; float mx = -1e30f;
  for (int j = 0; j < e; j++){ vals[j] = a[lane*e+j]; mx = fmaxf(mx, vals[j]); }
  for (int off = 32; off; off >>= 1) mx = fmaxf(mx, __shfl_xor(mx, off));
  float sum = 0.f;
  for (int j = 0; j < e; j++){ vals[j] = expf(vals[j]-mx); sum += vals[j]; }
  for (int off = 32; off; off >>= 1) sum += __shfl_xor(sum, off);
  float rinv = 1.f/sum;
  for (int j = 0; j < e; j++) a[lane*e+j] = vals[j]*rinv;
}

// ---------------- row LayerNorm core ----------------
__global__ void rownorm_kernel(const float* __restrict__ X, unsigned short* __restrict__ Y, int rows){
  int w = threadIdx.x >> 6, lane = threadIdx.x & 63;
  long row = (long)blockIdx.x*4 + w;
  if (row >= rows) return;
  const float4* xr = (const float4*)(X + row*DD);
  float4 xv = xr[lane];
  float s = xv.x+xv.y+xv.z+xv.w;
  float q = xv.x*xv.x+xv.y*xv.y+xv.z*xv.z+xv.w*xv.w;
  for (int off = 32; off; off >>= 1){ s += __shfl_xor(s, off); q += __shfl_xor(q, off); }
  float m = s*(1.f/256.f);
  float var = q*(1.f/256.f) - m*m;
  float rinv = rsqrtf(var + 1e-5f);
  ushort4 o;
  o.x = f2bf((xv.x-m)*rinv); o.y = f2bf((xv.y-m)*rinv);
  o.z = f2bf((xv.z-m)*rinv); o.w = f2bf((xv.w-m)*rinv);
  ((ushort4*)(Y + row*DD))[lane] = o;
}

// ---------------- multi-parameter f32 GEMM 64x64 (GCN path) ----------------
struct GP {
  const float* A; long sAb; int lda;
  const float* B; long sBb; int ldb;
  float* C; long sCb; int ldc;
  const int* pidx; const float* pe;
  int M, N, K; float alpha; int flags;
};
struct GP4 { GP p[4]; };

__global__ __launch_bounds__(256) void gemm_multi(GP4 g4){
  GP p = g4.p[blockIdx.z >> 3];
  int b = blockIdx.z & 7;
  int m0 = blockIdx.y*64, n0 = blockIdx.x*64;
  if (m0 >= p.M || n0 >= p.N) return;
  __shared__ __align__(16) unsigned short As[64*40];
  __shared__ __align__(16) unsigned short Bs[64*40];
  const float* Ab = p.A + (long)b*p.sAb;
  const float* Bb = p.B + (long)b*p.sBb;
  int t = threadIdx.x;
  int w = t >> 6, lane = t & 63, lrowi = lane & 15, lquad = lane >> 4;
  int wm = w >> 1, wn = w & 1;
  f32x4 acc[2][2];
  #pragma unroll
  for (int i = 0; i < 2; i++)
    #pragma unroll
    for (int j = 0; j < 2; j++) acc[i][j] = (f32x4){0.f,0.f,0.f,0.f};
  int am = t >> 2, akq = t & 3;
  for (int k0 = 0; k0 < p.K; k0 += 32){
    {
      const float4* s4 = (const float4*)(Ab + (long)(m0+am)*p.lda + k0 + akq*8);
      float4 u = s4[0], vv = s4[1];
      unsigned short tmp[8];
      tmp[0]=f2bf(u.x); tmp[1]=f2bf(u.y); tmp[2]=f2bf(u.z); tmp[3]=f2bf(u.w);
      tmp[4]=f2bf(vv.x); tmp[5]=f2bf(vv.y); tmp[6]=f2bf(vv.z); tmp[7]=f2bf(vv.w);
      *(uint4*)(&As[am*40 + akq*8]) = *(uint4*)tmp;
    }
    if (p.flags & FLAG_TRANSB){
      const float4* s4 = (const float4*)(Bb + (long)(n0+am)*p.ldb + k0 + akq*8);
      float4 u = s4[0], vv = s4[1];
      unsigned short tmp[8];
      tmp[0]=f2bf(u.x); tmp[1]=f2bf(u.y); tmp[2]=f2bf(u.z); tmp[3]=f2bf(u.w);
      tmp[4]=f2bf(vv.x); tmp[5]=f2bf(vv.y); tmp[6]=f2bf(vv.z); tmp[7]=f2bf(vv.w);
      *(uint4*)(&Bs[am*40 + akq*8]) = *(uint4*)tmp;
    } else {
      int bn = t & 63, bkb = (t >> 6)*8;
      #pragma unroll
      for (int j = 0; j < 8; j++)
        Bs[bn*40 + bkb + j] = f2bf(Bb[(long)(k0+bkb+j)*p.ldb + n0 + bn]);
    }
    __syncthreads();
    bf16x8 af[2], bfr[2];
    #pragma unroll
    for (int i = 0; i < 2; i++)
      af[i] = *(const bf16x8*)(&As[(wm*32 + i*16 + lrowi)*40 + lquad*8]);
    #pragma unroll
    for (int j = 0; j < 2; j++)
      bfr[j] = *(const bf16x8*)(&Bs[(wn*32 + j*16 + lrowi)*40 + lquad*8]);
    #pragma unroll
    for (int i = 0; i < 2; i++)
      #pragma unroll
      for (int j = 0; j < 2; j++)
        acc[i][j] = __builtin_amdgcn_mfma_f32_16x16x32_bf16(af[i], bfr[j], acc[i][j], 0, 0, 0);
    __syncthreads();
  }
  float* Cb = p.C + (long)b*p.sCb;
  #pragma unroll
  for (int i = 0; i < 2; i++)
    #pragma unroll
    for (int j = 0; j < 2; j++){
      int col = n0 + wn*32 + j*16 + lrowi;
      #pragma unroll
      for (int r = 0; r < 4; r++){
        int row = m0 + wm*32 + i*16 + lquad*4 + r;
        float v = p.alpha*acc[i][j][r];
        if (p.flags & FLAG_RELU) v = fmaxf(v, 0.f);
        if (p.pidx != nullptr){
          int idx = p.pidx[b*512 + row];
          v += p.pe[(long)idx*256 + col];
        }
        Cb[(long)row*p.ldc + col] = v;
      }
    }
}

// ---------------- fast 128x128 bf16 GEMM (K=256), 2-phase counted-vmcnt prefetch ----------------
template<typename OT, bool RES, bool GATE>
__device__ __forceinline__ void gemm128_body(
    const unsigned short* __restrict__ A, long sAb,
    const unsigned short* __restrict__ BT,
    OT* __restrict__ C, long sCb, int ldc,
    const float* __restrict__ R, long sRb,
    const float* __restrict__ bias, const float* __restrict__ gate,
    int bx, int by, int bz,
    unsigned short (&As)[2][4096], unsigned short (&Bs)[2][4096])
{
  int t = threadIdx.x;
  int w = t >> 6, lane = t & 63, lrowi = lane & 15, lquad = lane >> 4;
  int wm = w >> 1, wn = w & 1;
  int m0 = by*128, n0 = bx*128;
  const unsigned short* Ab = A + (long)bz*sAb + (long)m0*256;
  const unsigned short* Bb = BT + (long)n0*256;
  int g0 = t, g1 = 256 + t;
  int row0 = g0 >> 2, kq0 = g0 & 3;
  int row1 = g1 >> 2, kq1 = g1 & 3;
  f32x4 acc[4][4];
  #pragma unroll
  for (int i = 0; i < 4; i++)
    #pragma unroll
    for (int j = 0; j < 4; j++) acc[i][j] = (f32x4){0.f,0.f,0.f,0.f};

  auto stage = [&](int buf, int k0){
    gload16(Ab + (long)row0*256 + k0 + kq0*8, &As[buf][g0*8]);
    gload16(Ab + (long)row1*256 + k0 + kq1*8, &As[buf][g1*8]);
    gload16(Bb + (long)row0*256 + k0 + kq0*8, &Bs[buf][g0*8]);
    gload16(Bb + (long)row1*256 + k0 + kq1*8, &Bs[buf][g1*8]);
  };

  stage(0, 0);
  for (int it = 0; it < 8; it++){
    int cur = it & 1;
    if (it < 7){
      stage(cur ^ 1, (it+1)*32);
      __asm__ volatile("s_waitcnt vmcnt(4)" ::: "memory");   // current tile's 4 loads done
    } else {
      __asm__ volatile("s_waitcnt vmcnt(0)" ::: "memory");
    }
    __builtin_amdgcn_s_barrier();                            // tile visible to all waves
    bf16x8 af[4], bfr[4];
    #pragma unroll
    for (int i = 0; i < 4; i++)
      af[i] = *(const bf16x8*)(&As[cur][((wm*64 + i*16 + lrowi)*4 + lquad)*8]);
    #pragma unroll
    for (int j = 0; j < 4; j++)
      bfr[j] = *(const bf16x8*)(&Bs[cur][((wn*64 + j*16 + lrowi)*4 + lquad)*8]);
    #pragma unroll
    for (int i = 0; i < 4; i++)
      #pragma unroll
      for (int j = 0; j < 4; j++)
        acc[i][j] = __builtin_amdgcn_mfma_f32_16x16x32_bf16(af[i], bfr[j], acc[i][j], 0, 0, 0);
    __asm__ volatile("s_waitcnt lgkmcnt(0)" ::: "memory");   // reads of buf[cur] done
    __builtin_amdgcn_s_barrier();                            // before next iter overwrites buf[cur]
  }
  OT* Cb = C + (long)bz*sCb;
  const float* Rb = RES ? (R + (long)bz*sRb) : nullptr;
  #pragma unroll
  for (int j = 0; j < 4; j++){
    int col = n0 + wn*64 + j*16 + lrowi;
    float bv = bias[col];
    float gv = GATE ? gate[col] : 1.f;
    #pragma unroll
    for (int i = 0; i < 4; i++){
      #pragma unroll
      for (int r = 0; r < 4; r++){
        int row = m0 + wm*64 + i*16 + lquad*4 + r;
        float v = acc[i][j][r] + bv;
        if (GATE) v *= gv;
        if (RES) v += Rb[(long)row*256 + col];
        if constexpr (sizeof(OT) == 4) Cb[(long)row*ldc + col] = v;
        else                           Cb[(long)row*ldc + col] = f2bf(v);
      }
    }
  }
}

template<typename OT, bool RES, bool GATE>
__global__ __launch_bounds__(256) void gemm128(
    const unsigned short* __restrict__ A, long sAb,
    const unsigned short* __restrict__ BT,
    OT* __restrict__ C, long sCb, int ldc,
    const float* __restrict__ R, long sRb,
    const float* __restrict__ bias, const float* __restrict__ gate)
{
  __shared__ __align__(16) unsigned short As[2][4096];
  __shared__ __align__(16) unsigned short Bs[2][4096];
  gemm128_body<OT,RES,GATE>(A, sAb, BT, C, sCb, ldc, R, sRb, bias, gate,
                            blockIdx.x, blockIdx.y, blockIdx.z, As, Bs);
}

// two <ushort,false,false> GEMMs in one launch: set0 = (6,32) blocks, set1 = (2,3)
__global__ __launch_bounds__(256) void gemm128_pair(
    const unsigned short* __restrict__ A0, long sA0, const unsigned short* __restrict__ B0,
    unsigned short* __restrict__ C0, long sC0, int ldc0, const float* __restrict__ bias0,
    const unsigned short* __restrict__ A1, long sA1, const unsigned short* __restrict__ B1,
    unsigned short* __restrict__ C1, long sC1, int ldc1, const float* __restrict__ bias1)
{
  __shared__ __align__(16) unsigned short As[2][4096];
  __shared__ __align__(16) unsigned short Bs[2][4096];
  int x = blockIdx.x, z = blockIdx.z;
  if (x < 192){
    gemm128_body<unsigned short,false,false>(A0, sA0, B0, C0, sC0, ldc0, nullptr, 0, bias0, nullptr,
                                             x % 6, x / 6, z, As, Bs);
  } else {
    int xx = x - 192;
    gemm128_body<unsigned short,false,false>(A1, sA1, B1, C1, sC1, ldc1, nullptr, 0, bias1, nullptr,
                                             xx % 2, xx / 2, z, As, Bs);
  }
}

// ---------------- flash cross-attention, no-max softmax, 64-row K-tile ----------------
template<int NFRAG>
__global__ __launch_bounds__(256) void flash_kernel(
    const unsigned short* __restrict__ Q, long sQb, int ldq,
    const unsigned short* __restrict__ Kt, const unsigned short* __restrict__ Vt,
    long sKb, int ldkv,
    unsigned short* __restrict__ O, long sOb,
    float* __restrict__ Opart, float* __restrict__ Lpart,
    int Nq, int Nk, int nsplit)
{
  __shared__ __align__(16) unsigned short Kl[2][32*72];
  __shared__ __align__(16) unsigned short Vl[2][64*36];
  __shared__ __align__(16) unsigned short Pl[4*NFRAG*16*36];
  int b = blockIdx.z, h = blockIdx.y;
  int nqg = Nq / (64*NFRAG);
  int qg = blockIdx.x % nqg, split = blockIdx.x / nqg;
  int kchunk = Nk / nsplit;
  int kbeg = split*kchunk, kend = kbeg + kchunk;
  int t = threadIdx.x, w = t >> 6, lane = t & 63, lrowi = lane & 15, lquad = lane >> 4;
  int q0 = qg*(64*NFRAG) + w*(16*NFRAG);
  const unsigned short* Qb = Q + (long)b*sQb + h*DHH;
  const unsigned short* Kb = Kt + (long)b*sKb + h*DHH;
  const unsigned short* Vb = Vt + (long)b*sKb + h*DHH;
  bf16x8 qa[NFRAG][2];
  #pragma unroll
  for (int f = 0; f < NFRAG; f++)
    #pragma unroll
    for (int kt = 0; kt < 2; kt++)
      qa[f][kt] = *(const bf16x8*)(Qb + (long)(q0 + f*16 + lrowi)*ldq + kt*32 + lquad*8);

  f32x4 o[NFRAG][4];
  float psum[NFRAG][4];
  #pragma unroll
  for (int f = 0; f < NFRAG; f++)
    #pragma unroll
    for (int cj = 0; cj < 4; cj++){
      o[f][cj] = (f32x4){0.f,0.f,0.f,0.f};
      psum[f][cj] = 0.f;
    }
  int skq = t >> 3, sdq = (t & 7)*8;
  int skrow = ((skq & 1) << 4) | (skq >> 1);
  int vkq = t & 31, vdq = (t >> 5)*8;
  unsigned short* Pw = &Pl[w*(NFRAG*16*36)];

  for (int kt0 = kbeg; kt0 < kend; kt0 += 64){
    {
      uint4 k0v = *(const uint4*)(Kb + (long)(kt0+skq)*ldkv + sdq);
      uint4 v0v = *(const uint4*)(Vb + (long)(kt0+vkq)*ldkv + vdq);
      uint4 k1v = *(const uint4*)(Kb + (long)(kt0+32+skq)*ldkv + sdq);
      uint4 v1v = *(const uint4*)(Vb + (long)(kt0+32+vkq)*ldkv + vdq);
      *(uint4*)(&Kl[0][skrow*72 + sdq]) = k0v;
      const unsigned short* vp0 = (const unsigned short*)&v0v;
      #pragma unroll
      for (int j = 0; j < 8; j++) Vl[0][(vdq+j)*36 + vkq] = vp0[j];
      *(uint4*)(&Kl[1][skrow*72 + sdq]) = k1v;
      const unsigned short* vp1 = (const unsigned short*)&v1v;
      #pragma unroll
      for (int j = 0; j < 8; j++) Vl[1][(vdq+j)*36 + vkq] = vp1[j];
    }
    __syncthreads();
    #pragma unroll
    for (int s = 0; s < 2; s++){
      bf16x8 kb0 = *(const bf16x8*)(&Kl[s][(0*16+lrowi)*72 + lquad*8]);
      bf16x8 kb1 = *(const bf16x8*)(&Kl[s][(0*16+lrowi)*72 + 32 + lquad*8]);
      bf16x8 kb2 = *(const bf16x8*)(&Kl[s][(1*16+lrowi)*72 + lquad*8]);
      bf16x8 kb3 = *(const bf16x8*)(&Kl[s][(1*16+lrowi)*72 + 32 + lquad*8]);
      union { bf16x8 v8; bf16x4 v4[2]; } vbu[4];
      #pragma unroll
      for (int cj = 0; cj < 4; cj++){
        const unsigned short* vb = &Vl[s][(cj*16+lrowi)*36 + lquad*8];
        vbu[cj].v4[0] = *(const bf16x4*)vb;
        vbu[cj].v4[1] = *(const bf16x4*)(vb + 4);
      }
      #pragma unroll
      for (int f = 0; f < NFRAG; f++){
        f32x4 S0 = (f32x4){0.f,0.f,0.f,0.f}, S1 = (f32x4){0.f,0.f,0.f,0.f};
        __builtin_amdgcn_s_setprio(1);
        S0 = __builtin_amdgcn_mfma_f32_16x16x32_bf16(qa[f][0], kb0, S0, 0, 0, 0);
        S0 = __builtin_amdgcn_mfma_f32_16x16x32_bf16(qa[f][1], kb1, S0, 0, 0, 0);
        S1 = __builtin_amdgcn_mfma_f32_16x16x32_bf16(qa[f][0], kb2, S1, 0, 0, 0);
        S1 = __builtin_amdgcn_mfma_f32_16x16x32_bf16(qa[f][1], kb3, S1, 0, 0, 0);
        __builtin_amdgcn_s_setprio(0);
        unsigned short* Pf = Pw + f*(16*36);
        #pragma unroll
        for (int r = 0; r < 4; r++){
          float p0 = exp2f(S0[r]);           // even k-col (orig 2*lrowi)
          float p1 = exp2f(S1[r]);           // odd  k-col (orig 2*lrowi+1)
          psum[f][r] += p0 + p1;
          unsigned int pk;
          asm("v_cvt_pk_bf16_f32 %0, %1, %2" : "=v"(pk) : "v"(p0), "v"(p1));
          *(unsigned int*)(&Pf[(lquad*4+r)*36 + 2*lrowi]) = pk;
        }
      }
      __asm__ volatile("s_waitcnt lgkmcnt(0)" ::: "memory");
      #pragma unroll
      for (int f = 0; f < NFRAG; f++){
        const unsigned short* pp = &Pw[f*(16*36) + lrowi*36 + lquad*8];
        union { bf16x8 v8; bf16x4 v4[2]; } pa;
        pa.v4[0] = *(const bf16x4*)pp;
        pa.v4[1] = *(const bf16x4*)(pp + 4);
        __builtin_amdgcn_s_setprio(1);
        #pragma unroll
        for (int cj = 0; cj < 4; cj++)
          o[f][cj] = __builtin_amdgcn_mfma_f32_16x16x32_bf16(pa.v8, vbu[cj].v8, o[f][cj], 0, 0, 0);
        __builtin_amdgcn_s_setprio(0);
      }
    }
    __syncthreads();
  }
  float lsum[NFRAG][4];
  #pragma unroll
  for (int f = 0; f < NFRAG; f++)
    #pragma unroll
    for (int r = 0; r < 4; r++){
      float s = psum[f][r];
      #pragma unroll
      for (int off = 1; off < 16; off <<= 1) s += __shfl_xor(s, off);
      lsum[f][r] = s;
    }
  if (nsplit > 1){
    int p = (b*HH + h)*nsplit + split;
    float* Op = Opart + (long)p*Nq*DHH;
    #pragma unroll
    for (int f = 0; f < NFRAG; f++)
      #pragma unroll
      for (int r = 0; r < 4; r++){
        int row = q0 + f*16 + lquad*4 + r;
        #pragma unroll
        for (int cj = 0; cj < 4; cj++)
          Op[(long)row*DHH + cj*16 + lrowi] = o[f][cj][r];
        if (lrowi == 0) Lpart[(long)p*Nq + row] = lsum[f][r];
      }
  } else {
    unsigned short* Ob = O + (long)b*sOb + h*DHH;
    #pragma unroll
    for (int f = 0; f < NFRAG; f++)
      #pragma unroll
      for (int r = 0; r < 4; r++){
        float rl = 1.f/lsum[f][r];
        int row = q0 + f*16 + lquad*4 + r;
        #pragma unroll
        for (int cj = 0; cj < 4; cj++)
          Ob[(long)row*DD + cj*16 + lrowi] = f2bf(o[f][cj][r]*rl);
      }
  }
}

// ---------------- flash split combine ----------------
__global__ void flash_combine(const float* __restrict__ Opart, const float* __restrict__ Lpart,
                              unsigned short* __restrict__ O, long sOb, int Nq, int nsplit){
  int gr = blockIdx.x*4 + (threadIdx.x >> 6);
  int d = threadIdx.x & 63;
  int bh = gr / Nq, row = gr % Nq;
  float accO = 0.f, accL = 0.f;
  for (int s = 0; s < nsplit; s++){
    long p = (long)bh*nsplit + s;
    accL += Lpart[p*Nq + row];
    accO += Opart[(p*Nq + row)*DHH + d];
  }
  int b = bh / HH, h = bh % HH;
  O[(long)b*sOb + (long)row*DD + h*DHH + d] = f2bf(accO/accL);
}

// ---------------- host ----------------
extern "C" void kernel_launch(void* const* d_in, const int* in_sizes, int n_in,
                              void* d_out, int out_size, void* d_ws, size_t ws_size,
                              hipStream_t stream) {
  (void)in_sizes; (void)n_in; (void)out_size; (void)ws_size;
  const float* x        = (const float*)d_in[0];
  const int*   mask     = (const int*)d_in[1];
  const float* pos_emb  = (const float*)d_in[2];
  const float* sim_p_w  = (const float*)d_in[3];
  const float* sim_p_b  = (const float*)d_in[4];
  const float* sim_n_w  = (const float*)d_in[5];
  const float* sim_n_b  = (const float*)d_in[6];
  const float* adj_w    = (const float*)d_in[7];
  const float* gnn_p_w1 = (const float*)d_in[8];
  const float* gnn_p_w2 = (const float*)d_in[9];
  const float* gnn_n_w1 = (const float*)d_in[10];
  const float* gnn_n_w2 = (const float*)d_in[11];
  const float* ln1_g = (const float*)d_in[12]; const float* ln1_b = (const float*)d_in[13];
  const float* ln2_g = (const float*)d_in[14]; const float* ln2_b = (const float*)d_in[15];
  const float* ln3_g = (const float*)d_in[16]; const float* ln3_b = (const float*)d_in[17];
  const float* ln4_g = (const float*)d_in[18]; const float* ln4_b = (const float*)d_in[19];
  const float* ln5_g = (const float*)d_in[20]; const float* ln5_b = (const float*)d_in[21];
  const float* i2q_wq = (const float*)d_in[22];
  const float* i2q_wk = (const float*)d_in[23];
  const float* i2q_wv = (const float*)d_in[24];
  const float* i2q_wo = (const float*)d_in[25];
  const float* q2i_wq = (const float*)d_in[26];
  const float* q2i_wk = (const float*)d_in[27];
  const float* q2i_wv = (const float*)d_in[28];
  const float* q2i_wo = (const float*)d_in[29];
  const float* i2q_bo = (const float*)d_in[30];
  const float* q2i_bo = (const float*)d_in[31];
  const float* mlp_w  = (const float*)d_in[32];
  const float* mlp_b  = (const float*)d_in[33];
  const float* g_i2t  = (const float*)d_in[34];
  const float* g_t2i  = (const float*)d_in[35];

  float* out  = (float*)d_out;
  float* simP = out + (size_t)BB*NN*DD;
  float* simN = simP + (size_t)BB*NN;

  char* w8 = (char*)d_ws;
  size_t off = 0;
  auto take = [&](size_t bytes)->void*{
    void* p = (void*)(w8 + off);
    off += (bytes + 255) & ~(size_t)255;
    return p;
  };
  float* part   = (float*)take((size_t)BB*SCH*2*DD*4);
  float* pcnt   = (float*)take((size_t)BB*SCH*2*4);
  float* vvec   = (float*)take((size_t)BB*2*DD*4);
  float* cscal  = (float*)take((size_t)BB*2*4);
  int*   idxb   = (int*)take((size_t)BB*2*256*4);
  float* wb     = (float*)take((size_t)BB*2*256*4);
  float* node   = (float*)take((size_t)BB*384*DD*4);
  float* gA     = (float*)take((size_t)BB*384*DD*4);   // also t3
  float* gadjP  = (float*)take((size_t)BB*256*256*4);
  float* gadjN  = (float*)take((size_t)BB*128*128*4);
  float* query  = (float*)take((size_t)BB*384*DD*4);   // also t1
  float* query2 = (float*)take((size_t)BB*384*DD*4);   // also t2
  unsigned short* xhatq  = (unsigned short*)take((size_t)BB*384*DD*2);
  unsigned short* qh     = (unsigned short*)take((size_t)BB*384*DD*2);
  unsigned short* attnZ  = (unsigned short*)take((size_t)BB*384*DD*2);
  unsigned short* xhatq2 = (unsigned short*)take((size_t)BB*384*DD*2);
  unsigned short* kv2    = (unsigned short*)take((size_t)BB*384*512*2);
  unsigned short* xhat   = (unsigned short*)take((size_t)BB*NN*DD*2);
  unsigned short* kvq    = (unsigned short*)take((size_t)BB*NN*768*2);
  float* featb2 = (float*)take((size_t)BB*NN*DD*4);
  float* Lpart  = (float*)take((size_t)BB*HH*8*384*4);
  unsigned short* wTq1  = (unsigned short*)take((size_t)65536*2);
  unsigned short* wTbig = (unsigned short*)take((size_t)3*65536*2);
  unsigned short* wTkv2 = (unsigned short*)take((size_t)2*65536*2);
  unsigned short* wTmlp = (unsigned short*)take((size_t)65536*2);
  unsigned short* wTo1  = (unsigned short*)take((size_t)65536*2);
  unsigned short* wTo2  = (unsigned short*)take((size_t)65536*2);
  float* biasQ1  = (float*)take(256*4);
  float* biasBig = (float*)take(768*4);
  float* biasKV2 = (float*)take(512*4);
  float* biasMlp = (float*)take(256*4);
  // overlays (disjoint lifetimes):
  float* t1 = query;
  float* t2 = query2;
  float* t3 = gA;
  unsigned short* attn2 = xhat;
  unsigned short* xhat5 = kvq;
  float* Opart = featb2;

  const long sQ  = 384L*DD;
  const long sX  = (long)NN*DD;
  const float* NF = nullptr;

  // softmax scale (1/sqrt(dh)) * log2(e), folded into the Q projections
  const float QS = 0.125f * 1.44269504088896f;

  // ---- merged weight folds + stats_part (independent; one launch) ----
  FoldArgs fa;
  fa.W[0]=i2q_wq; fa.g[0]=ln1_g; fa.BT[0]=wTq1;            fa.sc[0]=QS;
  fa.W[1]=i2q_wk; fa.g[1]=ln2_g; fa.BT[1]=wTbig;           fa.sc[1]=1.f;
  fa.W[2]=i2q_wv; fa.g[2]=ln2_g; fa.BT[2]=wTbig + 256*256; fa.sc[2]=1.f;
  fa.W[3]=q2i_wq; fa.g[3]=ln3_g; fa.BT[3]=wTbig + 512*256; fa.sc[3]=QS;
  fa.W[4]=q2i_wk; fa.g[4]=ln4_g; fa.BT[4]=wTkv2;           fa.sc[4]=1.f;
  fa.W[5]=q2i_wv; fa.g[5]=ln4_g; fa.BT[5]=wTkv2 + 256*256; fa.sc[5]=1.f;
  fa.W[6]=mlp_w;  fa.g[6]=ln5_g; fa.BT[6]=wTmlp;           fa.sc[6]=1.f;
  fa.W[7]=i2q_wo; fa.g[7]=nullptr; fa.BT[7]=wTo1;          fa.sc[7]=1.f;
  fa.W[8]=q2i_wo; fa.g[8]=nullptr; fa.BT[8]=wTo2;          fa.sc[8]=1.f;
  BiasArgs ba;
  ba.W[0]=i2q_wq; ba.b[0]=ln1_b; ba.addb[0]=nullptr; ba.out[0]=biasQ1;     ba.sc[0]=QS;
  ba.W[1]=i2q_wk; ba.b[1]=ln2_b; ba.addb[1]=nullptr; ba.out[1]=biasBig;    ba.sc[1]=1.f;
  ba.W[2]=i2q_wv; ba.b[2]=ln2_b; ba.addb[2]=nullptr; ba.out[2]=biasBig+256; ba.sc[2]=1.f;
  ba.W[3]=q2i_wq; ba.b[3]=ln3_b; ba.addb[3]=nullptr; ba.out[3]=biasBig+512; ba.sc[3]=QS;
  ba.W[4]=q2i_wk; ba.b[4]=ln4_b; ba.addb[4]=nullptr; ba.out[4]=biasKV2;    ba.sc[4]=1.f;
  ba.W[5]=q2i_wv; ba.b[5]=ln4_b; ba.addb[5]=nullptr; ba.out[5]=biasKV2+256; ba.sc[5]=1.f;
  ba.W[6]=mlp_w;  ba.b[6]=ln5_b; ba.addb[6]=mlp_b;   ba.out[6]=biasMlp;    ba.sc[6]=1.f;
  fold_stats<<<dim3(64,18), 256, 0, stream>>>(fa, ba, x, mask, part, pcnt);

  // ---- stats reduce + matvec + cscal (one launch) / sims / topk+gather ----
  stats_sim<<<dim3(9, BB), 256, 0, stream>>>(part, pcnt, sim_p_w, sim_n_w,
                                             sim_p_b, sim_n_b, vvec, cscal);
  sim_norm_kernel<<<dim3(NN/4, BB), 256, 0, stream>>>(x, vvec, cscal, simP, simN, xhat);
  topk_radix<<<2*BB, 256, 0, stream>>>(simP, simN, x, idxb, wb, node);

  // ---- GCN (pos/neg paired) — separate launches (grid-wide sync costs ~100us/sync on MI355X) ----
  GP z = {};
  {
    GP4 g;
    g.p[0] = { node, 384L*DD, 256, adj_w, 0, 256, gA, 384L*DD, 256, nullptr, nullptr, 384, 256, 256, 1.f, 0 };
    g.p[1] = { node, 384L*DD, 256, gnn_p_w1, 0, 256, t1, 384L*DD, 256, nullptr, nullptr, 256, 256, 256, 1.f, 0 };
    g.p[2] = { node + 256L*DD, 384L*DD, 256, gnn_n_w1, 0, 256, t1 + 256L*DD, 384L*DD, 256, nullptr, nullptr, 128, 256, 256, 1.f, 0 };
    g.p[3] = z;
    gemm_multi<<<dim3(4,6,3*BB), 256, 0, stream>>>(g);
  }
  {
    GP4 g;
    g.p[0] = { gA, 384L*DD, 256, node, 384L*DD, 256, gadjP, 65536L, 256, nullptr, nullptr, 256, 256, 256, 0.0625f, FLAG_TRANSB };
    g.p[1] = { gA + 256L*DD, 384L*DD, 256, node + 256L*DD, 384L*DD, 256, gadjN, 16384L, 128, nullptr, nullptr, 128, 128, 256, 0.0625f, FLAG_TRANSB };
    g.p[2] = z; g.p[3] = z;
    gemm_multi<<<dim3(4,4,2*BB), 256, 0, stream>>>(g);
  }
  softmax_dual<<<768, 256, 0, stream>>>(gadjP, 256, 256, 65536L, BB*256,
                                        gadjN, 128, 128, 16384L, BB*128);
  {
    GP4 g;
    g.p[0] = { gadjP, 65536L, 256, t1, 384L*DD, 256, t2, 384L*DD, 256, nullptr, nullptr, 256, 256, 256, 1.f, FLAG_RELU };
    g.p[1] = { gadjN, 16384L, 128, t1 + 256L*DD, 384L*DD, 256, t2 + 256L*DD, 384L*DD, 256, nullptr, nullptr, 128, 256, 128, 1.f, FLAG_RELU };
    g.p[2] = z; g.p[3] = z;
    gemm_multi<<<dim3(4,4,2*BB), 256, 0, stream>>>(g);
  }
  {
    GP4 g;
    g.p[0] = { t2, 384L*DD, 256, gnn_p_w2, 0, 256, t3, 384L*DD, 256, nullptr, nullptr, 256, 256, 256, 1.f, 0 };
    g.p[1] = { t2 + 256L*DD, 384L*DD, 256, gnn_n_w2, 0, 256, t3 + 256L*DD, 384L*DD, 256, nullptr, nullptr, 128, 256, 256, 1.f, 0 };
    g.p[2] = z; g.p[3] = z;
    gemm_multi<<<dim3(4,4,2*BB), 256, 0, stream>>>(g);
  }
  {
    GP4 g;
    g.p[0] = { gadjP, 65536L, 256, t3, 384L*DD, 256, query, 384L*DD, 256, idxb, pos_emb, 256, 256, 256, 1.f, 0 };
    g.p[1] = { gadjN, 16384L, 128, t3 + 256L*DD, 384L*DD, 256, query + 256L*DD, 384L*DD, 256, idxb + 256, pos_emb, 128, 256, 128, 1.f, 0 };
    g.p[2] = z; g.p[3] = z;
    gemm_multi<<<dim3(4,4,2*BB), 256, 0, stream>>>(g);
  }

  // ---- LN core of query ----
  rownorm_kernel<<<BB*384/4, 256, 0, stream>>>(query, xhatq, BB*384);

  // (a)+(b) merged: qh = xhatq @ wq' + b'  and  [kh|vh|qh2] = xhat @ [wk'|wv'|wq2'] + b'
  gemm128_pair<<<dim3(198,1,BB),256,0,stream>>>(
      xhat, sX, wTbig, kvq, (long)NN*768, 768, biasBig,
      xhatq, sQ, wTq1, qh, sQ, 256, biasQ1);
  // i2q flash (NFRAG=3, K-split 8) + combine
  flash_kernel<3><<<dim3(2*8, HH, BB), 256, 0, stream>>>(
      qh, sQ, 256, kvq, kvq + 256, (long)NN*768, 768,
      attnZ, sQ, Opart, Lpart, 384, NN, 8);
  flash_combine<<<BB*HH*384/4, 256, 0, stream>>>(Opart, Lpart, attnZ, sQ, 384, 8);
  // (c) query2 = query + g_i2t .* (attnZ @ wo + bo)
  gemm128<float,true,true><<<dim3(2,3,BB),256,0,stream>>>(
      attnZ, sQ, wTo1, query2, sQ, 256, query, sQ, i2q_bo, g_i2t);

  // ---- q2i ----
  rownorm_kernel<<<BB*384/4, 256, 0, stream>>>(query2, xhatq2, BB*384);
  // (d) [k2|v2] = xhatq2 @ [wk2'|wv2'] + b'
  gemm128<unsigned short,false,false><<<dim3(4,3,BB),256,0,stream>>>(
      xhatq2, sQ, wTkv2, kv2, 384L*512, 512, NF, 0, biasKV2, NF);
  flash_kernel<2><<<dim3(32, HH, BB), 256, 0, stream>>>(
      kvq + 512, (long)NN*768, 768, kv2, kv2 + 256, 384L*512, 512,
      attn2, sX, nullptr, nullptr, NN, 384, 1);
  // (e) featb2 = x + g_t2i .* (attn2 @ wo + bo)
  gemm128<float,true,true><<<dim3(2,32,BB),256,0,stream>>>(
      attn2, sX, wTo2, featb2, sX, 256, x, sX, q2i_bo, g_t2i);

  // ---- final MLP ----
  rownorm_kernel<<<BB*NN/4, 256, 0, stream>>>(featb2, xhat5, BB*NN);
  gemm128<float,true,false><<<dim3(2,32,BB),256,0,stream>>>(
      xhat5, sX, wTmlp, out, sX, 256, featb2, sX, biasMlp, NF);
}